// Round 2
// baseline (1427.904 us; speedup 1.0000x reference)
//
#include <hip/hip_runtime.h>
#include <stdint.h>

typedef unsigned short u16;
typedef __attribute__((ext_vector_type(8))) _Float16 half8;
typedef __attribute__((ext_vector_type(4))) float floatx4;

// ---------- helpers ----------
__device__ inline float bflo(unsigned u){ return __uint_as_float(u << 16); }
__device__ inline float bfhi(unsigned u){ return __uint_as_float(u & 0xffff0000u); }
__device__ inline float bf1(u16 v){ return __uint_as_float(((unsigned)v) << 16); }
__device__ inline u16 f2bf(float f){
  unsigned u = __float_as_uint(f);
  u += 0x7fffu + ((u >> 16) & 1u);           // RNE
  return (u16)(u >> 16);
}
__device__ inline float dot8(uint4 w, float4 a, float4 b, float acc){
  acc = fmaf(bflo(w.x), a.x, acc); acc = fmaf(bfhi(w.x), a.y, acc);
  acc = fmaf(bflo(w.y), a.z, acc); acc = fmaf(bfhi(w.y), a.w, acc);
  acc = fmaf(bflo(w.z), b.x, acc); acc = fmaf(bfhi(w.z), b.y, acc);
  acc = fmaf(bflo(w.w), b.z, acc); acc = fmaf(bfhi(w.w), b.w, acc);
  return acc;
}

// canonical weight buffer offsets (u16 elements), d_in order (skipping inputs)
#define CW_SLOTS 0
#define CW_GIN   4096
#define CW_BIN   4352
#define CW_GS    4608
#define CW_BS    4864
#define CW_GM    5120
#define CW_BM    5376
#define CW_WQ    5632
#define CW_WK    71168
#define CW_WV    136704
#define CW_WIH   202240
#define CW_WHH   398848
#define CW_BIH   595456
#define CW_BHH   596224
#define CW_W1    596992
#define CW_B1    728064
#define CW_W2    728576
#define CW_B2    859648
#define CW_TOTAL 859904

// ---------- dtype probe: decode first 1024 u16 of `inputs` as bf16 ----------
// genuine bf16 data ~N(0,1) -> all finite & small; f32-backed data has random
// u16 patterns in the odd halves -> almost surely some |x|>1e6 or inf/nan.
__global__ void k_flag(const u16* __restrict__ probe, int* __restrict__ flag){
  int t = threadIdx.x;
  int bad = 0;
  #pragma unroll
  for (int i = 0; i < 4; i++){
    float x = bf1(probe[t + i * 256]);
    if (!(fabsf(x) < 1e6f)) bad = 1;     // catches inf/nan too
  }
  __shared__ int s;
  if (t == 0) s = 0;
  __syncthreads();
  if (bad) atomicOr(&s, 1);
  __syncthreads();
  if (t == 0) *flag = s;
}

// ---------- canonicalize all weight/bias arrays to bf16 in ws ----------
struct CanonArgs { const void* p[18]; };

__global__ void k_canon(CanonArgs a, const int* __restrict__ flag, u16* __restrict__ cw){
  const int off[19] = {CW_SLOTS, CW_GIN, CW_BIN, CW_GS, CW_BS, CW_GM, CW_BM, CW_WQ,
                       CW_WK, CW_WV, CW_WIH, CW_WHH, CW_BIH, CW_BHH, CW_W1, CW_B1,
                       CW_W2, CW_B2, CW_TOTAL};
  int i = blockIdx.x * 256 + threadIdx.x;
  if (i >= CW_TOTAL) return;
  int f32m = *flag;
  int j = 0;
  while (i >= off[j + 1]) j++;
  int local = i - off[j];
  float v = f32m ? ((const float*)a.p[j])[local] : bf1(((const u16*)a.p[j])[local]);
  cw[i] = f2bf(v);
}

// ---------- init: Wk/Wv -> fp16 [512][256]; broadcast slots -> f32 [512][256] ----------
__global__ void k_init(const u16* __restrict__ cw, float* __restrict__ slots,
                       _Float16* __restrict__ wkvh)
{
  int idx = blockIdx.x * 256 + threadIdx.x;      // 0..262143
  if (idx < 131072){
    wkvh[idx] = (_Float16)bf1(cw[CW_WK + idx]);  // Wk then Wv contiguous in cw
  } else {
    int i = idx - 131072;                         // (b*16+q)*256+d
    int d = i & 255;
    int q = (i >> 8) & 15;
    slots[i] = bf1(cw[CW_SLOTS + q * 256 + d]);
  }
}

__global__ void k_zero(float* __restrict__ p, int n){
  int i = blockIdx.x * 256 + threadIdx.x;
  if (i < n) p[i] = 0.f;
}

// ---------- K1: fused LayerNorm + [K|V] projection GEMM (MFMA fp16) ----------
// C[131072][512] = LN(inputs)[131072][256] @ W^T, W rows 0..255=Wk, 256..511=Wv
__global__ __launch_bounds__(256) void k1_lnkv(
    const void* __restrict__ inp, const u16* __restrict__ cw, const int* __restrict__ flag,
    const _Float16* __restrict__ wkvh, _Float16* __restrict__ kvh)
{
  int f32m = *flag;
  const float* inpf = (const float*)inp;
  const u16*   inpb = (const u16*)inp;
  int tid = threadIdx.x;
  int wv = tid >> 6, lane = tid & 63;
  int m16 = lane & 15, q4 = lane >> 4;
  long rowBase = (long)blockIdx.x * 64 + wv * 16;
  long myRow = rowBase + m16;

  // LN stats for row m16: this lane sums elems [q4*64, q4*64+64)
  float sum = 0.f, sq = 0.f;
  if (f32m){
    const float* rp = inpf + myRow * 256 + q4 * 64;
    #pragma unroll
    for (int i = 0; i < 16; i++){
      float4 v = ((const float4*)rp)[i];
      sum += v.x + v.y + v.z + v.w;
      sq = fmaf(v.x, v.x, sq); sq = fmaf(v.y, v.y, sq);
      sq = fmaf(v.z, v.z, sq); sq = fmaf(v.w, v.w, sq);
    }
  } else {
    const u16* rp = inpb + myRow * 256 + q4 * 64;
    #pragma unroll
    for (int i = 0; i < 8; i++){
      uint4 u = ((const uint4*)rp)[i];
      unsigned w[4] = {u.x, u.y, u.z, u.w};
      #pragma unroll
      for (int p = 0; p < 4; p++){
        float a = bflo(w[p]), b = bfhi(w[p]);
        sum += a + b; sq = fmaf(a, a, sq); sq = fmaf(b, b, sq);
      }
    }
  }
  sum += __shfl_xor(sum, 16); sum += __shfl_xor(sum, 32);
  sq  += __shfl_xor(sq , 16); sq  += __shfl_xor(sq , 32);
  float mu   = sum * (1.f/256.f);
  float var  = sq  * (1.f/256.f) - mu * mu;
  float rstd = rsqrtf(var + 1e-5f);

  floatx4 acc[32];
  #pragma unroll
  for (int i = 0; i < 32; i++) acc[i] = (floatx4)0.f;

  const u16* gin = cw + CW_GIN;
  const u16* bin = cw + CW_BIN;
  for (int s = 0; s < 8; s++){
    int dl = s * 32 + q4 * 8;
    float xv[8];
    if (f32m){
      float4 x0 = *(const float4*)(inpf + myRow * 256 + dl);
      float4 x1 = *(const float4*)(inpf + myRow * 256 + dl + 4);
      xv[0]=x0.x; xv[1]=x0.y; xv[2]=x0.z; xv[3]=x0.w;
      xv[4]=x1.x; xv[5]=x1.y; xv[6]=x1.z; xv[7]=x1.w;
    } else {
      uint4 xu = *(const uint4*)(inpb + myRow * 256 + dl);
      unsigned xw[4] = {xu.x, xu.y, xu.z, xu.w};
      #pragma unroll
      for (int p = 0; p < 4; p++){ xv[2*p] = bflo(xw[p]); xv[2*p+1] = bfhi(xw[p]); }
    }
    uint4 gu = *(const uint4*)(gin + dl);
    uint4 bu = *(const uint4*)(bin + dl);
    unsigned gw[4] = {gu.x,gu.y,gu.z,gu.w}, bw[4] = {bu.x,bu.y,bu.z,bu.w};
    half8 af;
    #pragma unroll
    for (int p = 0; p < 4; p++){
      af[2*p]   = (_Float16)((xv[2*p]   - mu) * rstd * bflo(gw[p]) + bflo(bw[p]));
      af[2*p+1] = (_Float16)((xv[2*p+1] - mu) * rstd * bfhi(gw[p]) + bfhi(bw[p]));
    }
    const _Float16* wbase = wkvh + m16 * 256 + dl;
    #pragma unroll
    for (int nt = 0; nt < 32; nt++){
      half8 bf8 = *(const half8*)(wbase + nt * 16 * 256);
      acc[nt] = __builtin_amdgcn_mfma_f32_16x16x32_f16(af, bf8, acc[nt], 0, 0, 0);
    }
  }
  long crow = rowBase + q4 * 4;                   // D: row = quad*4 + reg, col = lane&15
  #pragma unroll
  for (int nt = 0; nt < 32; nt++)
    #pragma unroll
    for (int r = 0; r < 4; r++)
      kvh[(crow + r) * 512 + nt * 16 + m16] = (_Float16)acc[nt][r];
}

// ---------- K2: slot LN + q = LN(slots) @ Wq^T * hd^-0.5 -> fp16 [512][256] ----------
__global__ __launch_bounds__(256) void k2_q(
    const float* __restrict__ slots, const u16* __restrict__ cw, _Float16* __restrict__ qh)
{
  const u16* gq = cw + CW_GS;
  const u16* bq = cw + CW_BS;
  const u16* Wq = cw + CW_WQ;
  int row = blockIdx.x, tid = threadIdx.x;
  int wv = tid >> 6, lane = tid & 63;
  float x = slots[row * 256 + tid];
  float s = x, s2 = x * x;
  #pragma unroll
  for (int m = 1; m < 64; m <<= 1){ s += __shfl_xor(s, m); s2 += __shfl_xor(s2, m); }
  __shared__ float red[8];
  if (lane == 0){ red[wv] = s; red[4 + wv] = s2; }
  __syncthreads();
  float tot  = red[0] + red[1] + red[2] + red[3];
  float tot2 = red[4] + red[5] + red[6] + red[7];
  float mu = tot * (1.f/256.f);
  float rstd = rsqrtf(tot2 * (1.f/256.f) - mu * mu + 1e-5f);
  __shared__ float sln[256];
  sln[tid] = (x - mu) * rstd * bf1(gq[tid]) + bf1(bq[tid]);
  __syncthreads();
  const u16* wr = Wq + tid * 256;
  float a = 0.f;
  for (int k = 0; k < 256; k += 8){
    uint4 wu = *(const uint4*)(wr + k);
    float4 l0 = *(const float4*)(sln + k);
    float4 l1 = *(const float4*)(sln + k + 4);
    a = dot8(wu, l0, l1, a);
  }
  qh[row * 256 + tid] = (_Float16)(a * 0.17677669529663687f);   // hd^-0.5
}

// ---------- K3: fused logits(MFMA) + joint softmax(128) + numer/denom accumulation ----------
__global__ __launch_bounds__(256) void k3_attn(
    const _Float16* __restrict__ kvh, const _Float16* __restrict__ qh,
    float* __restrict__ numer, float* __restrict__ denom,
    void* __restrict__ av_base, const int* __restrict__ flag, int lastIter)
{
  int f32m = *flag;
  int tid = threadIdx.x;
  int wv = tid >> 6, lane = tid & 63;
  int m16 = lane & 15, q4 = lane >> 4;
  int b = blockIdx.y, chunk = blockIdx.x;
  __shared__ float lds_l[16 * 129];               // [key][h*16+q]

  half8 qf[2];
  #pragma unroll
  for (int hh = 0; hh < 2; hh++){
    int h = wv * 2 + hh;
    qf[hh] = *(const half8*)(qh + (b * 16 + m16) * 256 + h * 32 + q4 * 8);
  }
  float pd[2] = {0.f, 0.f};
  float nr[2][8];
  #pragma unroll
  for (int hh = 0; hh < 2; hh++)
    #pragma unroll
    for (int e = 0; e < 8; e++) nr[hh][e] = 0.f;

  floatx4 z4 = (floatx4)0.f;
  for (int g2 = 0; g2 < 8; g2++){
    int key0 = chunk * 128 + g2 * 16;
    long rowb = (long)b * 4096 + key0;
    #pragma unroll
    for (int hh = 0; hh < 2; hh++){
      int h = wv * 2 + hh;
      half8 af = *(const half8*)(kvh + (rowb + m16) * 512 + h * 32 + q4 * 8);
      floatx4 d = __builtin_amdgcn_mfma_f32_16x16x32_f16(af, qf[hh], z4, 0, 0, 0);
      #pragma unroll
      for (int r = 0; r < 4; r++)
        lds_l[(q4 * 4 + r) * 129 + h * 16 + m16] = d[r];
    }
    __syncthreads();
    {
      int kk = tid >> 4, qq = tid & 15;
      float l[8];
      #pragma unroll
      for (int h8 = 0; h8 < 8; h8++) l[h8] = lds_l[kk * 129 + h8 * 16 + qq];
      float M = l[0];
      #pragma unroll
      for (int h8 = 1; h8 < 8; h8++) M = fmaxf(M, l[h8]);
      #pragma unroll
      for (int msk = 1; msk < 16; msk <<= 1) M = fmaxf(M, __shfl_xor(M, msk));
      float p[8], sl = 0.f;
      #pragma unroll
      for (int h8 = 0; h8 < 8; h8++){ p[h8] = __expf(l[h8] - M); sl += p[h8]; }
      float St = sl;
      #pragma unroll
      for (int msk = 1; msk < 16; msk <<= 1) St += __shfl_xor(St, msk);
      float rS = 1.f / St;
      #pragma unroll
      for (int h8 = 0; h8 < 8; h8++) lds_l[kk * 129 + h8 * 16 + qq] = p[h8] * rS;
      if (lastIter){
        long idx = 131072 + ((long)b * 4096 + key0 + kk) * 16 + qq;
        float av = sl * rS;
        if (f32m) ((float*)av_base)[idx] = av;
        else      ((u16*)av_base)[idx]   = f2bf(av);
      }
    }
    __syncthreads();
    for (int key = 0; key < 16; key++){
      const _Float16* vrow = kvh + (rowb + key) * 512 + 256;
      #pragma unroll
      for (int hh = 0; hh < 2; hh++){
        int h = wv * 2 + hh;
        float a = lds_l[key * 129 + h * 16 + m16];
        pd[hh] += a;
        half8 vvv = *(const half8*)(vrow + h * 32 + q4 * 8);
        #pragma unroll
        for (int e = 0; e < 8; e++) nr[hh][e] = fmaf(a, (float)vvv[e], nr[hh][e]);
      }
    }
    __syncthreads();
  }
  #pragma unroll
  for (int hh = 0; hh < 2; hh++){
    int h = wv * 2 + hh;
    if (q4 == 0) atomicAdd(&denom[(b * 8 + h) * 16 + m16], pd[hh]);
    #pragma unroll
    for (int e = 0; e < 8; e++)
      atomicAdd(&numer[((b * 8 + h) * 16 + m16) * 32 + q4 * 8 + e], nr[hh][e]);
  }
}

// ---------- K4a: GRU cell -> mid (f32) ----------
__global__ __launch_bounds__(256) void k4a_gru(
    const float* __restrict__ slots, const float* __restrict__ numer, const float* __restrict__ denom,
    const u16* __restrict__ cw, float* __restrict__ mid)
{
  const u16* wih = cw + CW_WIH;
  const u16* whh = cw + CW_WHH;
  const u16* bih = cw + CW_BIH;
  const u16* bhh = cw + CW_BHH;
  int jc = blockIdx.x, rg = blockIdx.y;
  int tid = threadIdx.x;
  __shared__ float u_s[8][256];
  __shared__ float h_s[8][256];
  {
    int hh = tid >> 5, dh = tid & 31;
    for (int i = 0; i < 8; i++){
      int row = rg * 8 + i;
      int b = row >> 4, slot = row & 15;
      float den = denom[(b * 8 + hh) * 16 + slot] + 1e-8f;
      u_s[i][tid] = numer[((b * 8 + hh) * 16 + slot) * 32 + dh] / den;
      h_s[i][tid] = slots[row * 256 + tid];
    }
  }
  __syncthreads();
  int rl = tid >> 5, jl = tid & 31;
  int j = jc * 32 + jl;
  int row = rg * 8 + rl;
  const u16* wir = wih + j * 256;
  const u16* wiz = wih + (256 + j) * 256;
  const u16* win = wih + (512 + j) * 256;
  const u16* whr = whh + j * 256;
  const u16* whz = whh + (256 + j) * 256;
  const u16* whn = whh + (512 + j) * 256;
  float air = 0, aiz = 0, ain = 0, ahr = 0, ahz = 0, ahn = 0;
  for (int k = 0; k < 256; k += 8){
    float4 u0 = *(const float4*)(&u_s[rl][k]);
    float4 u1 = *(const float4*)(&u_s[rl][k + 4]);
    float4 h0 = *(const float4*)(&h_s[rl][k]);
    float4 h1 = *(const float4*)(&h_s[rl][k + 4]);
    air = dot8(*(const uint4*)(wir + k), u0, u1, air);
    aiz = dot8(*(const uint4*)(wiz + k), u0, u1, aiz);
    ain = dot8(*(const uint4*)(win + k), u0, u1, ain);
    ahr = dot8(*(const uint4*)(whr + k), h0, h1, ahr);
    ahz = dot8(*(const uint4*)(whz + k), h0, h1, ahz);
    ahn = dot8(*(const uint4*)(whn + k), h0, h1, ahn);
  }
  float gr = air + bf1(bih[j])       + ahr + bf1(bhh[j]);
  float gz = aiz + bf1(bih[256 + j]) + ahz + bf1(bhh[256 + j]);
  float r = 1.f / (1.f + __expf(-gr));
  float z = 1.f / (1.f + __expf(-gz));
  float nn = tanhf(ain + bf1(bih[512 + j]) + r * (ahn + bf1(bhh[512 + j])));
  float h = h_s[rl][j];
  mid[row * 256 + j] = (1.f - z) * nn + z * h;
}

// ---------- K4b: LN + MLP + residual -> slots (f32), last iter also writes out ----------
__global__ __launch_bounds__(256) void k4b_mlp(
    const float* __restrict__ mid, const u16* __restrict__ cw,
    float* __restrict__ slots, void* __restrict__ out_base,
    const int* __restrict__ flag, int lastIter)
{
  int f32m = *flag;
  const u16* gm = cw + CW_GM;
  const u16* bm = cw + CW_BM;
  const u16* w1 = cw + CW_W1;
  const u16* b1 = cw + CW_B1;
  const u16* w2 = cw + CW_W2;
  const u16* b2 = cw + CW_B2;
  int row = blockIdx.x, tid = threadIdx.x;
  int wv = tid >> 6, lane = tid & 63;
  float x = mid[row * 256 + tid];
  float s = x, s2 = x * x;
  #pragma unroll
  for (int m = 1; m < 64; m <<= 1){ s += __shfl_xor(s, m); s2 += __shfl_xor(s2, m); }
  __shared__ float red[8];
  if (lane == 0){ red[wv] = s; red[4 + wv] = s2; }
  __syncthreads();
  float tot  = red[0] + red[1] + red[2] + red[3];
  float tot2 = red[4] + red[5] + red[6] + red[7];
  float mu = tot * (1.f/256.f);
  float rstd = rsqrtf(tot2 * (1.f/256.f) - mu * mu + 1e-5f);
  __shared__ float ls[256];
  __shared__ float h1[512];
  ls[tid] = (x - mu) * rstd * bf1(gm[tid]) + bf1(bm[tid]);
  __syncthreads();
  const u16* w1a = w1 + tid * 256;
  const u16* w1b = w1 + (tid + 256) * 256;
  float a0 = 0.f, a1 = 0.f;
  for (int k = 0; k < 256; k += 8){
    float4 l0 = *(const float4*)(ls + k);
    float4 l1 = *(const float4*)(ls + k + 4);
    a0 = dot8(*(const uint4*)(w1a + k), l0, l1, a0);
    a1 = dot8(*(const uint4*)(w1b + k), l0, l1, a1);
  }
  h1[tid]       = fmaxf(a0 + bf1(b1[tid]), 0.f);
  h1[tid + 256] = fmaxf(a1 + bf1(b1[tid + 256]), 0.f);
  __syncthreads();
  const u16* w2r = w2 + tid * 512;
  float a = 0.f;
  for (int k = 0; k < 512; k += 8){
    float4 l0 = *(const float4*)(h1 + k);
    float4 l1 = *(const float4*)(h1 + k + 4);
    a = dot8(*(const uint4*)(w2r + k), l0, l1, a);
  }
  float res = x + a + bf1(b2[tid]);
  slots[row * 256 + tid] = res;
  if (lastIter){
    int idx = row * 256 + tid;
    if (f32m) ((float*)out_base)[idx] = res;
    else      ((u16*)out_base)[idx]   = f2bf(res);
  }
}

// ---------- launch ----------
extern "C" void kernel_launch(void* const* d_in, const int* in_sizes, int n_in,
                              void* d_out, int out_size, void* d_ws, size_t ws_size,
                              hipStream_t stream)
{
  char* ws = (char*)d_ws;
  int*  flagp    = (int*)ws;                        // 4 B (reserve 256)
  u16*  cw       = (u16*)(ws + 256);                // 1719808 B -> 1720064
  _Float16* qh   = (_Float16*)(ws + 1720064);       //  262144 B -> 1982208
  _Float16* wkvh = (_Float16*)(ws + 1982208);       //  262144 B -> 2244352
  float* slots   = (float*)(ws + 2244352);          //  524288 B -> 2768640
  float* mid     = (float*)(ws + 2768640);          //  524288 B -> 3292928
  float* numer   = (float*)(ws + 3292928);          //  524288 B -> 3817216
  float* denom   = (float*)(ws + 3817216);          //   16384 B -> 3833600 (contiguous after numer)
  _Float16* kvh  = (_Float16*)(ws + 3833600);       // 134217728 B fp16 [131072][512] (k|v)

  CanonArgs ca;
  ca.p[0]  = d_in[0];   // slots
  ca.p[1]  = d_in[2];   // gin
  ca.p[2]  = d_in[3];   // bin
  ca.p[3]  = d_in[4];   // gs
  ca.p[4]  = d_in[5];   // bs
  ca.p[5]  = d_in[6];   // gm
  ca.p[6]  = d_in[7];   // bm
  ca.p[7]  = d_in[8];   // Wq
  ca.p[8]  = d_in[9];   // Wk
  ca.p[9]  = d_in[10];  // Wv
  ca.p[10] = d_in[11];  // wih
  ca.p[11] = d_in[12];  // whh
  ca.p[12] = d_in[13];  // bih
  ca.p[13] = d_in[14];  // bhh
  ca.p[14] = d_in[15];  // w1
  ca.p[15] = d_in[16];  // b1
  ca.p[16] = d_in[17];  // w2
  ca.p[17] = d_in[18];  // b2

  k_flag<<<1, 256, 0, stream>>>((const u16*)d_in[1], flagp);
  k_canon<<<(CW_TOTAL + 255) / 256, 256, 0, stream>>>(ca, flagp, cw);
  k_init<<<1024, 256, 0, stream>>>(cw, slots, wkvh);
  k1_lnkv<<<2048, 256, 0, stream>>>(d_in[1], cw, flagp, wkvh, kvh);
  for (int it = 0; it < 3; it++){
    int last = (it == 2) ? 1 : 0;
    k2_q<<<512, 256, 0, stream>>>(slots, cw, qh);
    k_zero<<<528, 256, 0, stream>>>(numer, 135168);        // numer + denom
    k3_attn<<<dim3(32, 32), 256, 0, stream>>>(kvh, qh, numer, denom, d_out, flagp, last);
    k4a_gru<<<dim3(8, 64), 256, 0, stream>>>(slots, numer, denom, cw, mid);
    k4b_mlp<<<512, 256, 0, stream>>>(mid, cw, slots, d_out, flagp, last);
  }
}

// Round 3
// 928.504 us; speedup vs baseline: 1.5379x; 1.5379x over previous
//
#include <hip/hip_runtime.h>
#include <stdint.h>

typedef unsigned short u16;
typedef __attribute__((ext_vector_type(8))) _Float16 half8;
typedef __attribute__((ext_vector_type(4))) _Float16 half4;
typedef __attribute__((ext_vector_type(4))) float floatx4;

// ---------- helpers ----------
__device__ inline float bflo(unsigned u){ return __uint_as_float(u << 16); }
__device__ inline float bfhi(unsigned u){ return __uint_as_float(u & 0xffff0000u); }
__device__ inline float bf1(u16 v){ return __uint_as_float(((unsigned)v) << 16); }
__device__ inline u16 f2bf(float f){
  unsigned u = __float_as_uint(f);
  u += 0x7fffu + ((u >> 16) & 1u);           // RNE
  return (u16)(u >> 16);
}
__device__ inline float dot8(uint4 w, float4 a, float4 b, float acc){
  acc = fmaf(bflo(w.x), a.x, acc); acc = fmaf(bfhi(w.x), a.y, acc);
  acc = fmaf(bflo(w.y), a.z, acc); acc = fmaf(bfhi(w.y), a.w, acc);
  acc = fmaf(bflo(w.z), b.x, acc); acc = fmaf(bfhi(w.z), b.y, acc);
  acc = fmaf(bflo(w.w), b.z, acc); acc = fmaf(bfhi(w.w), b.w, acc);
  return acc;
}

// canonical weight buffer offsets (u16 elements), d_in order (skipping inputs)
#define CW_SLOTS 0
#define CW_GIN   4096
#define CW_BIN   4352
#define CW_GS    4608
#define CW_BS    4864
#define CW_GM    5120
#define CW_BM    5376
#define CW_WQ    5632
#define CW_WK    71168
#define CW_WV    136704
#define CW_WIH   202240
#define CW_WHH   398848
#define CW_BIH   595456
#define CW_BHH   596224
#define CW_W1    596992
#define CW_B1    728064
#define CW_W2    728576
#define CW_B2    859648
#define CW_TOTAL 859904

// ---------- dtype probe ----------
__global__ void k_flag(const u16* __restrict__ probe, int* __restrict__ flag){
  int t = threadIdx.x;
  int bad = 0;
  #pragma unroll
  for (int i = 0; i < 4; i++){
    float x = bf1(probe[t + i * 256]);
    if (!(fabsf(x) < 1e6f)) bad = 1;
  }
  __shared__ int s;
  if (t == 0) s = 0;
  __syncthreads();
  if (bad) atomicOr(&s, 1);
  __syncthreads();
  if (t == 0) *flag = s;
}

// ---------- canonicalize all weight/bias arrays to bf16 in ws ----------
struct CanonArgs { const void* p[18]; };

__global__ void k_canon(CanonArgs a, const int* __restrict__ flag, u16* __restrict__ cw){
  const int off[19] = {CW_SLOTS, CW_GIN, CW_BIN, CW_GS, CW_BS, CW_GM, CW_BM, CW_WQ,
                       CW_WK, CW_WV, CW_WIH, CW_WHH, CW_BIH, CW_BHH, CW_W1, CW_B1,
                       CW_W2, CW_B2, CW_TOTAL};
  int i = blockIdx.x * 256 + threadIdx.x;
  if (i >= CW_TOTAL) return;
  int f32m = *flag;
  int j = 0;
  while (i >= off[j + 1]) j++;
  int local = i - off[j];
  float v = f32m ? ((const float*)a.p[j])[local] : bf1(((const u16*)a.p[j])[local]);
  cw[i] = f2bf(v);
}

// ---------- init: wkvh[c][d] = Wkv[c][d]*gin[d] (fp16); broadcast slots -> f32 ----------
__global__ void k_init(const u16* __restrict__ cw, float* __restrict__ slots,
                       _Float16* __restrict__ wkvh)
{
  int idx = blockIdx.x * 256 + threadIdx.x;      // 0..262143
  if (idx < 131072){
    float g = bf1(cw[CW_GIN + (idx & 255)]);
    wkvh[idx] = (_Float16)(bf1(cw[CW_WK + idx]) * g);   // Wk|Wv contiguous
  } else {
    int i = idx - 131072;
    int d = i & 255;
    int q = (i >> 8) & 15;
    slots[i] = bf1(cw[CW_SLOTS + q * 256 + d]);
  }
}

// beta[c] = sum_d bin[d] * Wkv[c][d]  (512 cols)
__global__ void k_beta(const u16* __restrict__ cw, float* __restrict__ beta){
  int c = blockIdx.x * 256 + threadIdx.x;
  if (c >= 512) return;
  float a = 0.f;
  for (int d = 0; d < 256; d++)
    a = fmaf(bf1(cw[CW_BIN + d]), bf1(cw[CW_WK + c * 256 + d]), a);
  beta[c] = a;
}

__global__ void k_zero(float* __restrict__ p, int n){
  int i = blockIdx.x * 256 + threadIdx.x;
  if (i < n) p[i] = 0.f;
}

// ---------- K0: per-row LN stats (mu, rstd) ----------
__global__ __launch_bounds__(256) void k0_stats(
    const void* __restrict__ inp, const int* __restrict__ flag, float2* __restrict__ stats)
{
  int f32m = *flag;
  int g = blockIdx.x * 256 + threadIdx.x;
  int row = g >> 4, l = g & 15;
  float sum = 0.f, sq = 0.f;
  if (f32m){
    const float* rp = (const float*)inp + row * 256 + l * 16;
    #pragma unroll
    for (int i = 0; i < 4; i++){
      float4 v = ((const float4*)rp)[i];
      sum += v.x + v.y + v.z + v.w;
      sq = fmaf(v.x, v.x, sq); sq = fmaf(v.y, v.y, sq);
      sq = fmaf(v.z, v.z, sq); sq = fmaf(v.w, v.w, sq);
    }
  } else {
    const u16* rp = (const u16*)inp + row * 256 + l * 16;
    #pragma unroll
    for (int i = 0; i < 2; i++){
      uint4 u = ((const uint4*)rp)[i];
      unsigned w[4] = {u.x, u.y, u.z, u.w};
      #pragma unroll
      for (int p = 0; p < 4; p++){
        float a = bflo(w[p]), b = bfhi(w[p]);
        sum += a + b; sq = fmaf(a, a, sq); sq = fmaf(b, b, sq);
      }
    }
  }
  #pragma unroll
  for (int m = 1; m < 16; m <<= 1){ sum += __shfl_xor(sum, m); sq += __shfl_xor(sq, m); }
  if (l == 0){
    float mu = sum * (1.f/256.f);
    float var = sq * (1.f/256.f) - mu * mu;
    stats[row] = make_float2(mu, rsqrtf(var + 1e-5f));
  }
}

// ---------- K1: GEMM with register-resident weights ----------
// grid (512 row-blocks of 256 rows, 2 n-blocks of 256 cols); wave owns 4 n-tiles (64 cols)
// out col<256 -> kh[row][col] (fp16); col>=256 -> vT[b][col-256][key] (fp16, keys contig)
__global__ __launch_bounds__(256) void k1_gemm(
    const void* __restrict__ inp, const int* __restrict__ flag,
    const float2* __restrict__ stats, const float* __restrict__ beta,
    const _Float16* __restrict__ wkvh, _Float16* __restrict__ kh, _Float16* __restrict__ vT)
{
  int f32m = *flag;
  int tid = threadIdx.x;
  int wv = tid >> 6, lane = tid & 63;
  int m16 = lane & 15, q4 = lane >> 4;
  int nb = blockIdx.y;
  long rowb0 = (long)blockIdx.x * 256;
  int colW = nb * 256 + wv * 64;                  // wave's base col

  // B-fragments: loaded once, stay in VGPRs (4 nt x 8 s)
  half8 bf[4][8];
  #pragma unroll
  for (int nt = 0; nt < 4; nt++)
    #pragma unroll
    for (int s = 0; s < 8; s++)
      bf[nt][s] = *(const half8*)(wkvh + (colW + nt * 16 + m16) * 256 + s * 32 + q4 * 8);

  float bet[4];
  #pragma unroll
  for (int nt = 0; nt < 4; nt++) bet[nt] = beta[colW + nt * 16 + m16];

  for (int rt = 0; rt < 16; rt++){
    long rowb = rowb0 + rt * 16;
    long myRow = rowb + m16;
    float2 st = stats[myRow];
    float mu = st.x, rstd = st.y;

    half8 af[8];
    if (f32m){
      const float* rp = (const float*)inp + myRow * 256 + q4 * 8;
      #pragma unroll
      for (int s = 0; s < 8; s++){
        float4 x0 = *(const float4*)(rp + s * 32);
        float4 x1 = *(const float4*)(rp + s * 32 + 4);
        af[s][0] = (_Float16)((x0.x - mu) * rstd); af[s][1] = (_Float16)((x0.y - mu) * rstd);
        af[s][2] = (_Float16)((x0.z - mu) * rstd); af[s][3] = (_Float16)((x0.w - mu) * rstd);
        af[s][4] = (_Float16)((x1.x - mu) * rstd); af[s][5] = (_Float16)((x1.y - mu) * rstd);
        af[s][6] = (_Float16)((x1.z - mu) * rstd); af[s][7] = (_Float16)((x1.w - mu) * rstd);
      }
    } else {
      const u16* rp = (const u16*)inp + myRow * 256 + q4 * 8;
      #pragma unroll
      for (int s = 0; s < 8; s++){
        uint4 xu = *(const uint4*)(rp + s * 32);
        unsigned xw[4] = {xu.x, xu.y, xu.z, xu.w};
        #pragma unroll
        for (int p = 0; p < 4; p++){
          af[s][2*p]   = (_Float16)((bflo(xw[p]) - mu) * rstd);
          af[s][2*p+1] = (_Float16)((bfhi(xw[p]) - mu) * rstd);
        }
      }
    }

    floatx4 acc[4];
    #pragma unroll
    for (int nt = 0; nt < 4; nt++){
      acc[nt][0] = bet[nt]; acc[nt][1] = bet[nt]; acc[nt][2] = bet[nt]; acc[nt][3] = bet[nt];
    }
    #pragma unroll
    for (int s = 0; s < 8; s++)
      #pragma unroll
      for (int nt = 0; nt < 4; nt++)
        acc[nt] = __builtin_amdgcn_mfma_f32_16x16x32_f16(af[s], bf[nt][s], acc[nt], 0, 0, 0);

    if (nb == 0){
      long crow = rowb + q4 * 4;
      #pragma unroll
      for (int nt = 0; nt < 4; nt++)
        #pragma unroll
        for (int r = 0; r < 4; r++)
          kh[(crow + r) * 256 + colW + nt * 16 + m16] = (_Float16)acc[nt][r];
    } else {
      int b = (int)(rowb >> 12);
      int key = ((int)rowb & 4095) + q4 * 4;
      #pragma unroll
      for (int nt = 0; nt < 4; nt++){
        int cv = (colW - 256) + nt * 16 + m16;
        half4 pk;
        pk[0] = (_Float16)acc[nt][0]; pk[1] = (_Float16)acc[nt][1];
        pk[2] = (_Float16)acc[nt][2]; pk[3] = (_Float16)acc[nt][3];
        *(half4*)(vT + ((long)b * 256 + cv) * 4096 + key) = pk;
      }
    }
  }
}

// ---------- K2: slot LN + q projection ----------
__global__ __launch_bounds__(256) void k2_q(
    const float* __restrict__ slots, const u16* __restrict__ cw, _Float16* __restrict__ qh)
{
  const u16* gq = cw + CW_GS;
  const u16* bq = cw + CW_BS;
  const u16* Wq = cw + CW_WQ;
  int row = blockIdx.x, tid = threadIdx.x;
  int wv = tid >> 6, lane = tid & 63;
  float x = slots[row * 256 + tid];
  float s = x, s2 = x * x;
  #pragma unroll
  for (int m = 1; m < 64; m <<= 1){ s += __shfl_xor(s, m); s2 += __shfl_xor(s2, m); }
  __shared__ float red[8];
  if (lane == 0){ red[wv] = s; red[4 + wv] = s2; }
  __syncthreads();
  float tot  = red[0] + red[1] + red[2] + red[3];
  float tot2 = red[4] + red[5] + red[6] + red[7];
  float mu = tot * (1.f/256.f);
  float rstd = rsqrtf(tot2 * (1.f/256.f) - mu * mu + 1e-5f);
  __shared__ float sln[256];
  sln[tid] = (x - mu) * rstd * bf1(gq[tid]) + bf1(bq[tid]);
  __syncthreads();
  const u16* wr = Wq + tid * 256;
  float a = 0.f;
  for (int k = 0; k < 256; k += 8){
    uint4 wu = *(const uint4*)(wr + k);
    float4 l0 = *(const float4*)(sln + k);
    float4 l1 = *(const float4*)(sln + k + 4);
    a = dot8(wu, l0, l1, a);
  }
  qh[row * 256 + tid] = (_Float16)(a * 0.17677669529663687f);
}

// ---------- K3: logits(MFMA) + joint softmax + MFMA numer/denom ----------
// grid (32 key-chunks of 128, 32 batches); wave w owns heads 2w,2w+1
__global__ __launch_bounds__(256) void k3_attn(
    const _Float16* __restrict__ kh, const _Float16* __restrict__ vT,
    const _Float16* __restrict__ qh,
    float* __restrict__ numer, float* __restrict__ denom,
    void* __restrict__ av_base, const int* __restrict__ flag, int lastIter)
{
  int f32m = *flag;
  int tid = threadIdx.x;
  int wv = tid >> 6, lane = tid & 63;
  int m16 = lane & 15, q4 = lane >> 4;
  int b = blockIdx.y, chunk = blockIdx.x;
  __shared__ float lds_l[32 * 129];               // [key 0..31][h*16+q]

  half8 qf[2];
  #pragma unroll
  for (int hh = 0; hh < 2; hh++){
    int h = wv * 2 + hh;
    qf[hh] = *(const half8*)(qh + (b * 16 + m16) * 256 + h * 32 + q4 * 8);
  }
  float pd[2] = {0.f, 0.f};
  floatx4 un[2][2];
  #pragma unroll
  for (int hh = 0; hh < 2; hh++)
    #pragma unroll
    for (int dt = 0; dt < 2; dt++) un[hh][dt] = (floatx4)0.f;

  floatx4 z4 = (floatx4)0.f;
  for (int g4 = 0; g4 < 4; g4++){
    int key0 = chunk * 128 + g4 * 32;
    // phase A: logits for 32 keys x 2 heads per wave
    #pragma unroll
    for (int sub = 0; sub < 2; sub++){
      long rowb = (long)b * 4096 + key0 + sub * 16;
      #pragma unroll
      for (int hh = 0; hh < 2; hh++){
        int h = wv * 2 + hh;
        half8 af = *(const half8*)(kh + (rowb + m16) * 256 + h * 32 + q4 * 8);
        floatx4 d = __builtin_amdgcn_mfma_f32_16x16x32_f16(af, qf[hh], z4, 0, 0, 0);
        #pragma unroll
        for (int r = 0; r < 4; r++)
          lds_l[(sub * 16 + q4 * 4 + r) * 129 + h * 16 + m16] = d[r];
      }
    }
    __syncthreads();
    // phase B: per-key joint softmax over 128 (h,q); each thread does 2 keys
    {
      int qq = tid & 15;
      #pragma unroll
      for (int half_ = 0; half_ < 2; half_++){
        int kk = (tid >> 4) + half_ * 16;
        float l[8];
        #pragma unroll
        for (int h8 = 0; h8 < 8; h8++) l[h8] = lds_l[kk * 129 + h8 * 16 + qq];
        float M = l[0];
        #pragma unroll
        for (int h8 = 1; h8 < 8; h8++) M = fmaxf(M, l[h8]);
        #pragma unroll
        for (int msk = 1; msk < 16; msk <<= 1) M = fmaxf(M, __shfl_xor(M, msk));
        float p[8], sl = 0.f;
        #pragma unroll
        for (int h8 = 0; h8 < 8; h8++){ p[h8] = __expf(l[h8] - M); sl += p[h8]; }
        float St = sl;
        #pragma unroll
        for (int msk = 1; msk < 16; msk <<= 1) St += __shfl_xor(St, msk);
        float rS = 1.f / St;
        #pragma unroll
        for (int h8 = 0; h8 < 8; h8++) lds_l[kk * 129 + h8 * 16 + qq] = p[h8] * rS;
        if (lastIter){
          long idx = 131072 + ((long)b * 4096 + key0 + kk) * 16 + qq;
          float av = sl * rS;
          if (f32m) ((float*)av_base)[idx] = av;
          else      ((u16*)av_base)[idx]   = f2bf(av);
        }
      }
    }
    __syncthreads();
    // phase C: U[d][q] += vT[d][key] * P[key][q] via MFMA over 32 keys
    #pragma unroll
    for (int hh = 0; hh < 2; hh++){
      int h = wv * 2 + hh;
      float pv[8];
      #pragma unroll
      for (int j = 0; j < 8; j++) pv[j] = lds_l[(q4 * 8 + j) * 129 + h * 16 + m16];
      float ps = 0.f;
      #pragma unroll
      for (int j = 0; j < 8; j++) ps += pv[j];
      pd[hh] += ps;
      half8 bfr;
      #pragma unroll
      for (int j = 0; j < 8; j++) bfr[j] = (_Float16)pv[j];
      #pragma unroll
      for (int dt = 0; dt < 2; dt++){
        half8 afr = *(const half8*)(vT + ((long)b * 256 + h * 32 + dt * 16 + m16) * 4096 + key0 + q4 * 8);
        un[hh][dt] = __builtin_amdgcn_mfma_f32_16x16x32_f16(afr, bfr, un[hh][dt], 0, 0, 0);
      }
    }
    __syncthreads();
  }
  #pragma unroll
  for (int hh = 0; hh < 2; hh++){
    int h = wv * 2 + hh;
    float t = pd[hh];
    t += __shfl_xor(t, 16); t += __shfl_xor(t, 32);
    if (q4 == 0) atomicAdd(&denom[(b * 8 + h) * 16 + m16], t);
    #pragma unroll
    for (int dt = 0; dt < 2; dt++)
      #pragma unroll
      for (int r = 0; r < 4; r++)
        atomicAdd(&numer[((b * 8 + h) * 16 + m16) * 32 + dt * 16 + q4 * 4 + r], un[hh][dt][r]);
  }
}

// ---------- K4a: GRU cell -> mid (f32) ----------
__global__ __launch_bounds__(256) void k4a_gru(
    const float* __restrict__ slots, const float* __restrict__ numer, const float* __restrict__ denom,
    const u16* __restrict__ cw, float* __restrict__ mid)
{
  const u16* wih = cw + CW_WIH;
  const u16* whh = cw + CW_WHH;
  const u16* bih = cw + CW_BIH;
  const u16* bhh = cw + CW_BHH;
  int jc = blockIdx.x, rg = blockIdx.y;
  int tid = threadIdx.x;
  __shared__ float u_s[8][256];
  __shared__ float h_s[8][256];
  {
    int hh = tid >> 5, dh = tid & 31;
    for (int i = 0; i < 8; i++){
      int row = rg * 8 + i;
      int b = row >> 4, slot = row & 15;
      float den = denom[(b * 8 + hh) * 16 + slot] + 1e-8f;
      u_s[i][tid] = numer[((b * 8 + hh) * 16 + slot) * 32 + dh] / den;
      h_s[i][tid] = slots[row * 256 + tid];
    }
  }
  __syncthreads();
  int rl = tid >> 5, jl = tid & 31;
  int j = jc * 32 + jl;
  int row = rg * 8 + rl;
  const u16* wir = wih + j * 256;
  const u16* wiz = wih + (256 + j) * 256;
  const u16* win = wih + (512 + j) * 256;
  const u16* whr = whh + j * 256;
  const u16* whz = whh + (256 + j) * 256;
  const u16* whn = whh + (512 + j) * 256;
  float air = 0, aiz = 0, ain = 0, ahr = 0, ahz = 0, ahn = 0;
  for (int k = 0; k < 256; k += 8){
    float4 u0 = *(const float4*)(&u_s[rl][k]);
    float4 u1 = *(const float4*)(&u_s[rl][k + 4]);
    float4 h0 = *(const float4*)(&h_s[rl][k]);
    float4 h1 = *(const float4*)(&h_s[rl][k + 4]);
    air = dot8(*(const uint4*)(wir + k), u0, u1, air);
    aiz = dot8(*(const uint4*)(wiz + k), u0, u1, aiz);
    ain = dot8(*(const uint4*)(win + k), u0, u1, ain);
    ahr = dot8(*(const uint4*)(whr + k), h0, h1, ahr);
    ahz = dot8(*(const uint4*)(whz + k), h0, h1, ahz);
    ahn = dot8(*(const uint4*)(whn + k), h0, h1, ahn);
  }
  float gr = air + bf1(bih[j])       + ahr + bf1(bhh[j]);
  float gz = aiz + bf1(bih[256 + j]) + ahz + bf1(bhh[256 + j]);
  float r = 1.f / (1.f + __expf(-gr));
  float z = 1.f / (1.f + __expf(-gz));
  float nn = tanhf(ain + bf1(bih[512 + j]) + r * (ahn + bf1(bhh[512 + j])));
  float h = h_s[rl][j];
  mid[row * 256 + j] = (1.f - z) * nn + z * h;
}

// ---------- K4b: LN + MLP + residual ----------
__global__ __launch_bounds__(256) void k4b_mlp(
    const float* __restrict__ mid, const u16* __restrict__ cw,
    float* __restrict__ slots, void* __restrict__ out_base,
    const int* __restrict__ flag, int lastIter)
{
  int f32m = *flag;
  const u16* gm = cw + CW_GM;
  const u16* bm = cw + CW_BM;
  const u16* w1 = cw + CW_W1;
  const u16* b1 = cw + CW_B1;
  const u16* w2 = cw + CW_W2;
  const u16* b2 = cw + CW_B2;
  int row = blockIdx.x, tid = threadIdx.x;
  int wv = tid >> 6, lane = tid & 63;
  float x = mid[row * 256 + tid];
  float s = x, s2 = x * x;
  #pragma unroll
  for (int m = 1; m < 64; m <<= 1){ s += __shfl_xor(s, m); s2 += __shfl_xor(s2, m); }
  __shared__ float red[8];
  if (lane == 0){ red[wv] = s; red[4 + wv] = s2; }
  __syncthreads();
  float tot  = red[0] + red[1] + red[2] + red[3];
  float tot2 = red[4] + red[5] + red[6] + red[7];
  float mu = tot * (1.f/256.f);
  float rstd = rsqrtf(tot2 * (1.f/256.f) - mu * mu + 1e-5f);
  __shared__ float ls[256];
  __shared__ float h1[512];
  ls[tid] = (x - mu) * rstd * bf1(gm[tid]) + bf1(bm[tid]);
  __syncthreads();
  const u16* w1a = w1 + tid * 256;
  const u16* w1b = w1 + (tid + 256) * 256;
  float a0 = 0.f, a1 = 0.f;
  for (int k = 0; k < 256; k += 8){
    float4 l0 = *(const float4*)(ls + k);
    float4 l1 = *(const float4*)(ls + k + 4);
    a0 = dot8(*(const uint4*)(w1a + k), l0, l1, a0);
    a1 = dot8(*(const uint4*)(w1b + k), l0, l1, a1);
  }
  h1[tid]       = fmaxf(a0 + bf1(b1[tid]), 0.f);
  h1[tid + 256] = fmaxf(a1 + bf1(b1[tid + 256]), 0.f);
  __syncthreads();
  const u16* w2r = w2 + tid * 512;
  float a = 0.f;
  for (int k = 0; k < 512; k += 8){
    float4 l0 = *(const float4*)(h1 + k);
    float4 l1 = *(const float4*)(h1 + k + 4);
    a = dot8(*(const uint4*)(w2r + k), l0, l1, a);
  }
  float res = x + a + bf1(b2[tid]);
  slots[row * 256 + tid] = res;
  if (lastIter){
    int idx = row * 256 + tid;
    if (f32m) ((float*)out_base)[idx] = res;
    else      ((u16*)out_base)[idx]   = f2bf(res);
  }
}

// ---------- launch ----------
extern "C" void kernel_launch(void* const* d_in, const int* in_sizes, int n_in,
                              void* d_out, int out_size, void* d_ws, size_t ws_size,
                              hipStream_t stream)
{
  char* ws = (char*)d_ws;
  int*  flagp    = (int*)ws;                        // [0,256)
  u16*  cw       = (u16*)(ws + 256);                // 1719808 -> 1720064
  _Float16* qh   = (_Float16*)(ws + 1720064);       //  262144 -> 1982208
  _Float16* wkvh = (_Float16*)(ws + 1982208);       //  262144 -> 2244352
  float* slots   = (float*)(ws + 2244352);          //  524288 -> 2768640
  float* mid     = (float*)(ws + 2768640);          //  524288 -> 3292928
  float* numer   = (float*)(ws + 3292928);          //  524288 -> 3817216
  float* denom   = (float*)(ws + 3817216);          //   16384 -> 3833600
  _Float16* kh   = (_Float16*)(ws + 3833600);       // 67108864 -> 70942464
  _Float16* vT   = (_Float16*)(ws + 70942464);      // 67108864 -> 138051328
  // aliases (non-overlapping lifetimes):
  float2* stats  = (float2*)(ws + 2768640);         // 1 MB over mid+numer; dead before iters
  float*  beta   = (float*)(ws + 3817216);          // 2 KB in denom region; dead before iters

  CanonArgs ca;
  ca.p[0]  = d_in[0];   ca.p[1]  = d_in[2];   ca.p[2]  = d_in[3];
  ca.p[3]  = d_in[4];   ca.p[4]  = d_in[5];   ca.p[5]  = d_in[6];
  ca.p[6]  = d_in[7];   ca.p[7]  = d_in[8];   ca.p[8]  = d_in[9];
  ca.p[9]  = d_in[10];  ca.p[10] = d_in[11];  ca.p[11] = d_in[12];
  ca.p[12] = d_in[13];  ca.p[13] = d_in[14];  ca.p[14] = d_in[15];
  ca.p[15] = d_in[16];  ca.p[16] = d_in[17];  ca.p[17] = d_in[18];

  k_flag<<<1, 256, 0, stream>>>((const u16*)d_in[1], flagp);
  k_canon<<<(CW_TOTAL + 255) / 256, 256, 0, stream>>>(ca, flagp, cw);
  k_init<<<1024, 256, 0, stream>>>(cw, slots, wkvh);
  k_beta<<<2, 256, 0, stream>>>(cw, beta);
  k0_stats<<<8192, 256, 0, stream>>>(d_in[1], flagp, stats);
  k1_gemm<<<dim3(512, 2), 256, 0, stream>>>(d_in[1], flagp, stats, beta, wkvh, kh, vT);
  for (int it = 0; it < 3; it++){
    int last = (it == 2) ? 1 : 0;
    k2_q<<<512, 256, 0, stream>>>(slots, cw, qh);
    k_zero<<<528, 256, 0, stream>>>(numer, 135168);
    k3_attn<<<dim3(32, 32), 256, 0, stream>>>(kh, vT, qh, numer, denom, d_out, flagp, last);
    k4a_gru<<<dim3(8, 64), 256, 0, stream>>>(slots, numer, denom, cw, mid);
    k4b_mlp<<<512, 256, 0, stream>>>(mid, cw, slots, d_out, flagp, last);
  }
}

// Round 5
// 821.664 us; speedup vs baseline: 1.7378x; 1.1300x over previous
//
#include <hip/hip_runtime.h>
#include <stdint.h>

typedef unsigned short u16;
typedef __attribute__((ext_vector_type(8))) _Float16 half8;
typedef __attribute__((ext_vector_type(4))) _Float16 half4;
typedef __attribute__((ext_vector_type(4))) float floatx4;

// ---------- helpers ----------
__device__ inline float bflo(unsigned u){ return __uint_as_float(u << 16); }
__device__ inline float bfhi(unsigned u){ return __uint_as_float(u & 0xffff0000u); }
__device__ inline float bf1(u16 v){ return __uint_as_float(((unsigned)v) << 16); }
__device__ inline u16 f2bf(float f){
  unsigned u = __float_as_uint(f);
  u += 0x7fffu + ((u >> 16) & 1u);           // RNE
  return (u16)(u >> 16);
}
__device__ inline float dot8(uint4 w, float4 a, float4 b, float acc){
  acc = fmaf(bflo(w.x), a.x, acc); acc = fmaf(bfhi(w.x), a.y, acc);
  acc = fmaf(bflo(w.y), a.z, acc); acc = fmaf(bfhi(w.y), a.w, acc);
  acc = fmaf(bflo(w.z), b.x, acc); acc = fmaf(bfhi(w.z), b.y, acc);
  acc = fmaf(bflo(w.w), b.z, acc); acc = fmaf(bfhi(w.w), b.w, acc);
  return acc;
}

// canonical weight buffer offsets (u16 elements), d_in order (skipping inputs)
#define CW_SLOTS 0
#define CW_GIN   4096
#define CW_BIN   4352
#define CW_GS    4608
#define CW_BS    4864
#define CW_GM    5120
#define CW_BM    5376
#define CW_WQ    5632
#define CW_WK    71168
#define CW_WV    136704
#define CW_WIH   202240
#define CW_WHH   398848
#define CW_BIH   595456
#define CW_BHH   596224
#define CW_W1    596992
#define CW_B1    728064
#define CW_W2    728576
#define CW_B2    859648
#define CW_TOTAL 859904

#define NPART 16
#define PART_STRIDE 135168   // 131072 numer + 4096 denom

// ---------- dtype probe ----------
__global__ void k_flag(const u16* __restrict__ probe, int* __restrict__ flag){
  int t = threadIdx.x;
  int bad = 0;
  #pragma unroll
  for (int i = 0; i < 4; i++){
    float x = bf1(probe[t + i * 256]);
    if (!(fabsf(x) < 1e6f)) bad = 1;
  }
  __shared__ int s;
  if (t == 0) s = 0;
  __syncthreads();
  if (bad) atomicOr(&s, 1);
  __syncthreads();
  if (t == 0) *flag = s;
}

// ---------- canonicalize all weight/bias arrays to bf16 in ws ----------
struct CanonArgs { const void* p[18]; };

__global__ void k_canon(CanonArgs a, const int* __restrict__ flag, u16* __restrict__ cw){
  const int off[19] = {CW_SLOTS, CW_GIN, CW_BIN, CW_GS, CW_BS, CW_GM, CW_BM, CW_WQ,
                       CW_WK, CW_WV, CW_WIH, CW_WHH, CW_BIH, CW_BHH, CW_W1, CW_B1,
                       CW_W2, CW_B2, CW_TOTAL};
  int i = blockIdx.x * 256 + threadIdx.x;
  if (i >= CW_TOTAL) return;
  int f32m = *flag;
  int j = 0;
  while (i >= off[j + 1]) j++;
  int local = i - off[j];
  float v = f32m ? ((const float*)a.p[j])[local] : bf1(((const u16*)a.p[j])[local]);
  cw[i] = f2bf(v);
}

// ---------- init: wkvh[c][d] = Wkv[c][d]*gin[d] (fp16); broadcast slots -> f32 ----------
__global__ void k_init(const u16* __restrict__ cw, float* __restrict__ slots,
                       _Float16* __restrict__ wkvh)
{
  int idx = blockIdx.x * 256 + threadIdx.x;      // 0..262143
  if (idx < 131072){
    float g = bf1(cw[CW_GIN + (idx & 255)]);
    wkvh[idx] = (_Float16)(bf1(cw[CW_WK + idx]) * g);   // Wk|Wv contiguous
  } else {
    int i = idx - 131072;
    int d = i & 255;
    int q = (i >> 8) & 15;
    slots[i] = bf1(cw[CW_SLOTS + q * 256 + d]);
  }
}

// beta[c] = sum_d bin[d] * Wkv[c][d]  (512 cols)
__global__ void k_beta(const u16* __restrict__ cw, float* __restrict__ beta){
  int c = blockIdx.x * 256 + threadIdx.x;
  if (c >= 512) return;
  float a = 0.f;
  for (int d = 0; d < 256; d++)
    a = fmaf(bf1(cw[CW_BIN + d]), bf1(cw[CW_WK + c * 256 + d]), a);
  beta[c] = a;
}

__global__ void k_zero(float* __restrict__ p, int n){
  int i = blockIdx.x * 256 + threadIdx.x;
  if (i < n) p[i] = 0.f;
}

// ---------- K1: fused LN-stats + GEMM with register-resident weights ----------
// grid (512 row-blocks of 256 rows, 2 n-blocks of 256 cols); wave owns 4 n-tiles (64 cols)
// out col<256 -> kh[row][col] (fp16); col>=256 -> vT[b][col-256][key] (fp16)
__global__ __launch_bounds__(256) void k1_gemm(
    const void* __restrict__ inp, const int* __restrict__ flag,
    const float* __restrict__ beta,
    const _Float16* __restrict__ wkvh, _Float16* __restrict__ kh, _Float16* __restrict__ vT)
{
  int f32m = *flag;
  int tid = threadIdx.x;
  int wv = tid >> 6, lane = tid & 63;
  int m16 = lane & 15, q4 = lane >> 4;
  int nb = blockIdx.y;
  long rowb0 = (long)blockIdx.x * 256;
  int colW = nb * 256 + wv * 64;                  // wave's base col

  __shared__ float2 sst[256];

  // ---- LN stats: thread t owns row rowb0+t (256 elements!) ----
  {
    float sum = 0.f, sq = 0.f;
    if (f32m){
      const float* rp = (const float*)inp + (rowb0 + tid) * 256;
      #pragma unroll 4
      for (int i = 0; i < 64; i++){                    // 64 x float4 = 256 floats
        float4 v = ((const float4*)rp)[i];
        sum += v.x + v.y + v.z + v.w;
        sq = fmaf(v.x, v.x, sq); sq = fmaf(v.y, v.y, sq);
        sq = fmaf(v.z, v.z, sq); sq = fmaf(v.w, v.w, sq);
      }
    } else {
      const u16* rp = (const u16*)inp + (rowb0 + tid) * 256;
      #pragma unroll 4
      for (int i = 0; i < 32; i++){                    // 32 x uint4 = 256 bf16
        uint4 u = ((const uint4*)rp)[i];
        unsigned w[4] = {u.x, u.y, u.z, u.w};
        #pragma unroll
        for (int p = 0; p < 4; p++){
          float a = bflo(w[p]), b = bfhi(w[p]);
          sum += a + b; sq = fmaf(a, a, sq); sq = fmaf(b, b, sq);
        }
      }
    }
    float mu = sum * (1.f/256.f);
    float var = sq * (1.f/256.f) - mu * mu;
    sst[tid] = make_float2(mu, rsqrtf(var + 1e-5f));
  }

  // ---- B-fragments: loaded once, stay in VGPRs (4 nt x 8 s) ----
  half8 bfr[4][8];
  #pragma unroll
  for (int nt = 0; nt < 4; nt++)
    #pragma unroll
    for (int s = 0; s < 8; s++)
      bfr[nt][s] = *(const half8*)(wkvh + (colW + nt * 16 + m16) * 256 + s * 32 + q4 * 8);

  float bet[4];
  #pragma unroll
  for (int nt = 0; nt < 4; nt++) bet[nt] = beta[colW + nt * 16 + m16];

  __syncthreads();

  for (int rt = 0; rt < 16; rt++){
    long rowb = rowb0 + rt * 16;
    long myRow = rowb + m16;
    float2 st = sst[rt * 16 + m16];
    float mu = st.x, rstd = st.y;

    half8 af[8];
    if (f32m){
      const float* rp = (const float*)inp + myRow * 256 + q4 * 8;
      #pragma unroll
      for (int s = 0; s < 8; s++){
        float4 x0 = *(const float4*)(rp + s * 32);
        float4 x1 = *(const float4*)(rp + s * 32 + 4);
        af[s][0] = (_Float16)((x0.x - mu) * rstd); af[s][1] = (_Float16)((x0.y - mu) * rstd);
        af[s][2] = (_Float16)((x0.z - mu) * rstd); af[s][3] = (_Float16)((x0.w - mu) * rstd);
        af[s][4] = (_Float16)((x1.x - mu) * rstd); af[s][5] = (_Float16)((x1.y - mu) * rstd);
        af[s][6] = (_Float16)((x1.z - mu) * rstd); af[s][7] = (_Float16)((x1.w - mu) * rstd);
      }
    } else {
      const u16* rp = (const u16*)inp + myRow * 256 + q4 * 8;
      #pragma unroll
      for (int s = 0; s < 8; s++){
        uint4 xu = *(const uint4*)(rp + s * 32);
        unsigned xw[4] = {xu.x, xu.y, xu.z, xu.w};
        #pragma unroll
        for (int p = 0; p < 4; p++){
          af[s][2*p]   = (_Float16)((bflo(xw[p]) - mu) * rstd);
          af[s][2*p+1] = (_Float16)((bfhi(xw[p]) - mu) * rstd);
        }
      }
    }

    floatx4 acc[4];
    #pragma unroll
    for (int nt = 0; nt < 4; nt++){
      acc[nt][0] = bet[nt]; acc[nt][1] = bet[nt]; acc[nt][2] = bet[nt]; acc[nt][3] = bet[nt];
    }
    #pragma unroll
    for (int s = 0; s < 8; s++)
      #pragma unroll
      for (int nt = 0; nt < 4; nt++)
        acc[nt] = __builtin_amdgcn_mfma_f32_16x16x32_f16(af[s], bfr[nt][s], acc[nt], 0, 0, 0);

    if (nb == 0){
      long crow = rowb + q4 * 4;
      #pragma unroll
      for (int nt = 0; nt < 4; nt++)
        #pragma unroll
        for (int r = 0; r < 4; r++)
          kh[(crow + r) * 256 + colW + nt * 16 + m16] = (_Float16)acc[nt][r];
    } else {
      int b = (int)(rowb >> 12);
      int key = ((int)rowb & 4095) + q4 * 4;
      #pragma unroll
      for (int nt = 0; nt < 4; nt++){
        int cv = (colW - 256) + nt * 16 + m16;
        half4 pk;
        pk[0] = (_Float16)acc[nt][0]; pk[1] = (_Float16)acc[nt][1];
        pk[2] = (_Float16)acc[nt][2]; pk[3] = (_Float16)acc[nt][3];
        *(half4*)(vT + ((long)b * 256 + cv) * 4096 + key) = pk;
      }
    }
  }
}

// ---------- K2: slot LN + q projection ----------
__global__ __launch_bounds__(256) void k2_q(
    const float* __restrict__ slots, const u16* __restrict__ cw, _Float16* __restrict__ qh)
{
  const u16* gq = cw + CW_GS;
  const u16* bq = cw + CW_BS;
  const u16* Wq = cw + CW_WQ;
  int row = blockIdx.x, tid = threadIdx.x;
  int wv = tid >> 6, lane = tid & 63;
  float x = slots[row * 256 + tid];
  float s = x, s2 = x * x;
  #pragma unroll
  for (int m = 1; m < 64; m <<= 1){ s += __shfl_xor(s, m); s2 += __shfl_xor(s2, m); }
  __shared__ float red[8];
  if (lane == 0){ red[wv] = s; red[4 + wv] = s2; }
  __syncthreads();
  float tot  = red[0] + red[1] + red[2] + red[3];
  float tot2 = red[4] + red[5] + red[6] + red[7];
  float mu = tot * (1.f/256.f);
  float rstd = rsqrtf(tot2 * (1.f/256.f) - mu * mu + 1e-5f);
  __shared__ float sln[256];
  sln[tid] = (x - mu) * rstd * bf1(gq[tid]) + bf1(bq[tid]);
  __syncthreads();
  const u16* wr = Wq + tid * 256;
  float a = 0.f;
  for (int k = 0; k < 256; k += 8){
    uint4 wu = *(const uint4*)(wr + k);
    float4 l0 = *(const float4*)(sln + k);
    float4 l1 = *(const float4*)(sln + k + 4);
    a = dot8(wu, l0, l1, a);
  }
  qh[row * 256 + tid] = (_Float16)(a * 0.17677669529663687f);
}

// ---------- K3: logits(MFMA) + joint softmax + MFMA numer/denom ----------
// grid (16 key-chunks of 256, 32 batches); wave w owns heads 2w,2w+1
__global__ __launch_bounds__(256) void k3_attn(
    const _Float16* __restrict__ kh, const _Float16* __restrict__ vT,
    const _Float16* __restrict__ qh,
    float* __restrict__ numer, float* __restrict__ denom,
    float* __restrict__ part, int use_part,
    void* __restrict__ av_base, const int* __restrict__ flag, int lastIter)
{
  int f32m = *flag;
  int tid = threadIdx.x;
  int wv = tid >> 6, lane = tid & 63;
  int m16 = lane & 15, q4 = lane >> 4;
  int b = blockIdx.y, chunk = blockIdx.x;
  __shared__ float lds_l[32 * 129];               // [key 0..31][h*16+q]

  half8 qf[2];
  #pragma unroll
  for (int hh = 0; hh < 2; hh++){
    int h = wv * 2 + hh;
    qf[hh] = *(const half8*)(qh + (b * 16 + m16) * 256 + h * 32 + q4 * 8);
  }
  float pd[2] = {0.f, 0.f};
  floatx4 un[2][2];
  #pragma unroll
  for (int hh = 0; hh < 2; hh++)
    #pragma unroll
    for (int dt = 0; dt < 2; dt++) un[hh][dt] = (floatx4)0.f;

  floatx4 z4 = (floatx4)0.f;
  for (int g4 = 0; g4 < 8; g4++){
    int key0 = chunk * 256 + g4 * 32;
    // phase A: logits for 32 keys x 2 heads per wave
    #pragma unroll
    for (int sub = 0; sub < 2; sub++){
      long rowb = (long)b * 4096 + key0 + sub * 16;
      #pragma unroll
      for (int hh = 0; hh < 2; hh++){
        int h = wv * 2 + hh;
        half8 af = *(const half8*)(kh + (rowb + m16) * 256 + h * 32 + q4 * 8);
        floatx4 d = __builtin_amdgcn_mfma_f32_16x16x32_f16(af, qf[hh], z4, 0, 0, 0);
        #pragma unroll
        for (int r = 0; r < 4; r++)
          lds_l[(sub * 16 + q4 * 4 + r) * 129 + h * 16 + m16] = d[r];
      }
    }
    __syncthreads();
    // phase B: per-key joint softmax over 128 (h,q); each thread does 2 keys
    {
      int qq = tid & 15;
      #pragma unroll
      for (int half_ = 0; half_ < 2; half_++){
        int kk = (tid >> 4) + half_ * 16;
        float l[8];
        #pragma unroll
        for (int h8 = 0; h8 < 8; h8++) l[h8] = lds_l[kk * 129 + h8 * 16 + qq];
        float M = l[0];
        #pragma unroll
        for (int h8 = 1; h8 < 8; h8++) M = fmaxf(M, l[h8]);
        #pragma unroll
        for (int msk = 1; msk < 16; msk <<= 1) M = fmaxf(M, __shfl_xor(M, msk));
        float p[8], sl = 0.f;
        #pragma unroll
        for (int h8 = 0; h8 < 8; h8++){ p[h8] = __expf(l[h8] - M); sl += p[h8]; }
        float St = sl;
        #pragma unroll
        for (int msk = 1; msk < 16; msk <<= 1) St += __shfl_xor(St, msk);
        float rS = 1.f / St;
        #pragma unroll
        for (int h8 = 0; h8 < 8; h8++) lds_l[kk * 129 + h8 * 16 + qq] = p[h8] * rS;
        if (lastIter){
          long idx = 131072 + ((long)b * 4096 + key0 + kk) * 16 + qq;
          float av = sl * rS;
          if (f32m) ((float*)av_base)[idx] = av;
          else      ((u16*)av_base)[idx]   = f2bf(av);
        }
      }
    }
    __syncthreads();
    // phase C: U[d][q] += vT[d][key] * P[key][q] via MFMA over 32 keys
    #pragma unroll
    for (int hh = 0; hh < 2; hh++){
      int h = wv * 2 + hh;
      float pv[8];
      #pragma unroll
      for (int j = 0; j < 8; j++) pv[j] = lds_l[(q4 * 8 + j) * 129 + h * 16 + m16];
      float ps = 0.f;
      #pragma unroll
      for (int j = 0; j < 8; j++) ps += pv[j];
      pd[hh] += ps;
      half8 bfr;
      #pragma unroll
      for (int j = 0; j < 8; j++) bfr[j] = (_Float16)pv[j];
      #pragma unroll
      for (int dt = 0; dt < 2; dt++){
        half8 afr = *(const half8*)(vT + ((long)b * 256 + h * 32 + dt * 16 + m16) * 4096 + key0 + q4 * 8);
        un[hh][dt] = __builtin_amdgcn_mfma_f32_16x16x32_f16(afr, bfr, un[hh][dt], 0, 0, 0);
      }
    }
    __syncthreads();
  }
  if (use_part){
    float* pn = part + (long)chunk * PART_STRIDE;
    #pragma unroll
    for (int hh = 0; hh < 2; hh++){
      int h = wv * 2 + hh;
      float t = pd[hh];
      t += __shfl_xor(t, 16); t += __shfl_xor(t, 32);
      if (q4 == 0) pn[131072 + (b * 8 + h) * 16 + m16] = t;
      #pragma unroll
      for (int dt = 0; dt < 2; dt++)
        *(floatx4*)(&pn[((b * 8 + h) * 16 + m16) * 32 + dt * 16 + q4 * 4]) = un[hh][dt];
    }
  } else {
    #pragma unroll
    for (int hh = 0; hh < 2; hh++){
      int h = wv * 2 + hh;
      float t = pd[hh];
      t += __shfl_xor(t, 16); t += __shfl_xor(t, 32);
      if (q4 == 0) atomicAdd(&denom[(b * 8 + h) * 16 + m16], t);
      #pragma unroll
      for (int dt = 0; dt < 2; dt++)
        #pragma unroll
        for (int r = 0; r < 4; r++)
          atomicAdd(&numer[((b * 8 + h) * 16 + m16) * 32 + dt * 16 + q4 * 4 + r], un[hh][dt][r]);
    }
  }
}

// ---------- reduce partial numer/denom ----------
__global__ void k_reduce(const float* __restrict__ part, float* __restrict__ numer){
  int i = blockIdx.x * 256 + threadIdx.x;
  if (i >= PART_STRIDE) return;
  float s = 0.f;
  #pragma unroll
  for (int c = 0; c < NPART; c++) s += part[(long)c * PART_STRIDE + i];
  numer[i] = s;   // denom is contiguous after numer
}

// ---------- K4a: GRU cell -> mid (f32) ----------
__global__ __launch_bounds__(256) void k4a_gru(
    const float* __restrict__ slots, const float* __restrict__ numer, const float* __restrict__ denom,
    const u16* __restrict__ cw, float* __restrict__ mid)
{
  const u16* wih = cw + CW_WIH;
  const u16* whh = cw + CW_WHH;
  const u16* bih = cw + CW_BIH;
  const u16* bhh = cw + CW_BHH;
  int jc = blockIdx.x, rg = blockIdx.y;
  int tid = threadIdx.x;
  __shared__ float u_s[8][256];
  __shared__ float h_s[8][256];
  {
    int hh = tid >> 5, dh = tid & 31;
    for (int i = 0; i < 8; i++){
      int row = rg * 8 + i;
      int b = row >> 4, slot = row & 15;
      float den = denom[(b * 8 + hh) * 16 + slot] + 1e-8f;
      u_s[i][tid] = numer[((b * 8 + hh) * 16 + slot) * 32 + dh] / den;
      h_s[i][tid] = slots[row * 256 + tid];
    }
  }
  __syncthreads();
  int rl = tid >> 5, jl = tid & 31;
  int j = jc * 32 + jl;
  int row = rg * 8 + rl;
  const u16* wir = wih + j * 256;
  const u16* wiz = wih + (256 + j) * 256;
  const u16* win = wih + (512 + j) * 256;
  const u16* whr = whh + j * 256;
  const u16* whz = whh + (256 + j) * 256;
  const u16* whn = whh + (512 + j) * 256;
  float air = 0, aiz = 0, ain = 0, ahr = 0, ahz = 0, ahn = 0;
  for (int k = 0; k < 256; k += 8){
    float4 u0 = *(const float4*)(&u_s[rl][k]);
    float4 u1 = *(const float4*)(&u_s[rl][k + 4]);
    float4 h0 = *(const float4*)(&h_s[rl][k]);
    float4 h1 = *(const float4*)(&h_s[rl][k + 4]);
    air = dot8(*(const uint4*)(wir + k), u0, u1, air);
    aiz = dot8(*(const uint4*)(wiz + k), u0, u1, aiz);
    ain = dot8(*(const uint4*)(win + k), u0, u1, ain);
    ahr = dot8(*(const uint4*)(whr + k), h0, h1, ahr);
    ahz = dot8(*(const uint4*)(whz + k), h0, h1, ahz);
    ahn = dot8(*(const uint4*)(whn + k), h0, h1, ahn);
  }
  float gr = air + bf1(bih[j])       + ahr + bf1(bhh[j]);
  float gz = aiz + bf1(bih[256 + j]) + ahz + bf1(bhh[256 + j]);
  float r = 1.f / (1.f + __expf(-gr));
  float z = 1.f / (1.f + __expf(-gz));
  float nn = tanhf(ain + bf1(bih[512 + j]) + r * (ahn + bf1(bhh[512 + j])));
  float h = h_s[rl][j];
  mid[row * 256 + j] = (1.f - z) * nn + z * h;
}

// ---------- K4b: LN + MLP + residual ----------
__global__ __launch_bounds__(256) void k4b_mlp(
    const float* __restrict__ mid, const u16* __restrict__ cw,
    float* __restrict__ slots, void* __restrict__ out_base,
    const int* __restrict__ flag, int lastIter)
{
  int f32m = *flag;
  const u16* gm = cw + CW_GM;
  const u16* bm = cw + CW_BM;
  const u16* w1 = cw + CW_W1;
  const u16* b1 = cw + CW_B1;
  const u16* w2 = cw + CW_W2;
  const u16* b2 = cw + CW_B2;
  int row = blockIdx.x, tid = threadIdx.x;
  int wv = tid >> 6, lane = tid & 63;
  float x = mid[row * 256 + tid];
  float s = x, s2 = x * x;
  #pragma unroll
  for (int m = 1; m < 64; m <<= 1){ s += __shfl_xor(s, m); s2 += __shfl_xor(s2, m); }
  __shared__ float red[8];
  if (lane == 0){ red[wv] = s; red[4 + wv] = s2; }
  __syncthreads();
  float tot  = red[0] + red[1] + red[2] + red[3];
  float tot2 = red[4] + red[5] + red[6] + red[7];
  float mu = tot * (1.f/256.f);
  float rstd = rsqrtf(tot2 * (1.f/256.f) - mu * mu + 1e-5f);
  __shared__ float ls[256];
  __shared__ float h1[512];
  ls[tid] = (x - mu) * rstd * bf1(gm[tid]) + bf1(bm[tid]);
  __syncthreads();
  const u16* w1a = w1 + tid * 256;
  const u16* w1b = w1 + (tid + 256) * 256;
  float a0 = 0.f, a1 = 0.f;
  for (int k = 0; k < 256; k += 8){
    float4 l0 = *(const float4*)(ls + k);
    float4 l1 = *(const float4*)(ls + k + 4);
    a0 = dot8(*(const uint4*)(w1a + k), l0, l1, a0);
    a1 = dot8(*(const uint4*)(w1b + k), l0, l1, a1);
  }
  h1[tid]       = fmaxf(a0 + bf1(b1[tid]), 0.f);
  h1[tid + 256] = fmaxf(a1 + bf1(b1[tid + 256]), 0.f);
  __syncthreads();
  const u16* w2r = w2 + tid * 512;
  float a = 0.f;
  for (int k = 0; k < 512; k += 8){
    float4 l0 = *(const float4*)(h1 + k);
    float4 l1 = *(const float4*)(h1 + k + 4);
    a = dot8(*(const uint4*)(w2r + k), l0, l1, a);
  }
  float res = x + a + bf1(b2[tid]);
  slots[row * 256 + tid] = res;
  if (lastIter){
    int idx = row * 256 + tid;
    if (f32m) ((float*)out_base)[idx] = res;
    else      ((u16*)out_base)[idx]   = f2bf(res);
  }
}

// ---------- launch ----------
extern "C" void kernel_launch(void* const* d_in, const int* in_sizes, int n_in,
                              void* d_out, int out_size, void* d_ws, size_t ws_size,
                              hipStream_t stream)
{
  char* ws = (char*)d_ws;
  int*  flagp    = (int*)ws;                        // [0,256)
  u16*  cw       = (u16*)(ws + 256);                // 1719808 -> 1720064
  _Float16* qh   = (_Float16*)(ws + 1720064);       //  262144 -> 1982208
  _Float16* wkvh = (_Float16*)(ws + 1982208);       //  262144 -> 2244352
  float* slots   = (float*)(ws + 2244352);          //  524288 -> 2768640
  float* mid     = (float*)(ws + 2768640);          //  524288 -> 3292928
  float* numer   = (float*)(ws + 3292928);          //  524288 -> 3817216
  float* denom   = (float*)(ws + 3817216);          //   16384 -> 3833600
  _Float16* kh   = (_Float16*)(ws + 3833600);       // 67108864 -> 70942464
  _Float16* vT   = (_Float16*)(ws + 70942464);      // 67108864 -> 138051328
  float* part    = (float*)(ws + 138051328);        // 8650752 -> 146702080
  float* beta    = (float*)(ws + 3817216);          // alias in denom region (dead before loop)

  int use_part = (ws_size >= 146702080UL) ? 1 : 0;

  CanonArgs ca;
  ca.p[0]  = d_in[0];   ca.p[1]  = d_in[2];   ca.p[2]  = d_in[3];
  ca.p[3]  = d_in[4];   ca.p[4]  = d_in[5];   ca.p[5]  = d_in[6];
  ca.p[6]  = d_in[7];   ca.p[7]  = d_in[8];   ca.p[8]  = d_in[9];
  ca.p[9]  = d_in[10];  ca.p[10] = d_in[11];  ca.p[11] = d_in[12];
  ca.p[12] = d_in[13];  ca.p[13] = d_in[14];  ca.p[14] = d_in[15];
  ca.p[15] = d_in[16];  ca.p[16] = d_in[17];  ca.p[17] = d_in[18];

  k_flag<<<1, 256, 0, stream>>>((const u16*)d_in[1], flagp);
  k_canon<<<(CW_TOTAL + 255) / 256, 256, 0, stream>>>(ca, flagp, cw);
  k_init<<<1024, 256, 0, stream>>>(cw, slots, wkvh);
  k_beta<<<2, 256, 0, stream>>>(cw, beta);
  k1_gemm<<<dim3(512, 2), 256, 0, stream>>>(d_in[1], flagp, beta, wkvh, kh, vT);
  for (int it = 0; it < 3; it++){
    int last = (it == 2) ? 1 : 0;
    k2_q<<<512, 256, 0, stream>>>(slots, cw, qh);
    if (!use_part) k_zero<<<528, 256, 0, stream>>>(numer, 135168);
    k3_attn<<<dim3(16, 32), 256, 0, stream>>>(kh, vT, qh, numer, denom, part, use_part,
                                              d_out, flagp, last);
    if (use_part) k_reduce<<<528, 256, 0, stream>>>(part, numer);
    k4a_gru<<<dim3(8, 64), 256, 0, stream>>>(slots, numer, denom, cw, mid);
    k4b_mlp<<<512, 256, 0, stream>>>(mid, cw, slots, d_out, flagp, last);
  }
}

// Round 6
// 812.062 us; speedup vs baseline: 1.7584x; 1.0118x over previous
//
#include <hip/hip_runtime.h>
#include <stdint.h>

typedef unsigned short u16;
typedef __attribute__((ext_vector_type(8))) _Float16 half8;
typedef __attribute__((ext_vector_type(4))) _Float16 half4;
typedef __attribute__((ext_vector_type(4))) float floatx4;

// ---------- helpers ----------
__device__ inline float bflo(unsigned u){ return __uint_as_float(u << 16); }
__device__ inline float bfhi(unsigned u){ return __uint_as_float(u & 0xffff0000u); }
__device__ inline float bf1(u16 v){ return __uint_as_float(((unsigned)v) << 16); }
__device__ inline u16 f2bf(float f){
  unsigned u = __float_as_uint(f);
  u += 0x7fffu + ((u >> 16) & 1u);           // RNE
  return (u16)(u >> 16);
}
__device__ inline float dot8(uint4 w, float4 a, float4 b, float acc){
  acc = fmaf(bflo(w.x), a.x, acc); acc = fmaf(bfhi(w.x), a.y, acc);
  acc = fmaf(bflo(w.y), a.z, acc); acc = fmaf(bfhi(w.y), a.w, acc);
  acc = fmaf(bflo(w.z), b.x, acc); acc = fmaf(bfhi(w.z), b.y, acc);
  acc = fmaf(bflo(w.w), b.z, acc); acc = fmaf(bfhi(w.w), b.w, acc);
  return acc;
}

// canonical weight buffer offsets (u16 elements), d_in order (skipping inputs)
#define CW_SLOTS 0
#define CW_GIN   4096
#define CW_BIN   4352
#define CW_GS    4608
#define CW_BS    4864
#define CW_GM    5120
#define CW_BM    5376
#define CW_WQ    5632
#define CW_WK    71168
#define CW_WV    136704
#define CW_WIH   202240
#define CW_WHH   398848
#define CW_BIH   595456
#define CW_BHH   596224
#define CW_W1    596992
#define CW_B1    728064
#define CW_W2    728576
#define CW_B2    859648
#define CW_TOTAL 859904

#define PART_STRIDE 135168   // 131072 numer + 4096 denom (floats)

// ---------- dtype probe ----------
__global__ void k_flag(const u16* __restrict__ probe, int* __restrict__ flag){
  int t = threadIdx.x;
  int bad = 0;
  #pragma unroll
  for (int i = 0; i < 4; i++){
    float x = bf1(probe[t + i * 256]);
    if (!(fabsf(x) < 1e6f)) bad = 1;
  }
  __shared__ int s;
  if (t == 0) s = 0;
  __syncthreads();
  if (bad) atomicOr(&s, 1);
  __syncthreads();
  if (t == 0) *flag = s;
}

// ---------- canonicalize all weight/bias arrays to bf16 in ws ----------
struct CanonArgs { const void* p[18]; };

__global__ void k_canon(CanonArgs a, const int* __restrict__ flag, u16* __restrict__ cw){
  const int off[19] = {CW_SLOTS, CW_GIN, CW_BIN, CW_GS, CW_BS, CW_GM, CW_BM, CW_WQ,
                       CW_WK, CW_WV, CW_WIH, CW_WHH, CW_BIH, CW_BHH, CW_W1, CW_B1,
                       CW_W2, CW_B2, CW_TOTAL};
  int i = blockIdx.x * 256 + threadIdx.x;
  if (i >= CW_TOTAL) return;
  int f32m = *flag;
  int j = 0;
  while (i >= off[j + 1]) j++;
  int local = i - off[j];
  float v = f32m ? ((const float*)a.p[j])[local] : bf1(((const u16*)a.p[j])[local]);
  cw[i] = f2bf(v);
}

// ---------- init: wkvh[c][d] = Wkv[c][d]*gin[d] (fp16); broadcast slots -> f32 ----------
__global__ void k_init(const u16* __restrict__ cw, float* __restrict__ slots,
                       _Float16* __restrict__ wkvh)
{
  int idx = blockIdx.x * 256 + threadIdx.x;      // 0..262143
  if (idx < 131072){
    float g = bf1(cw[CW_GIN + (idx & 255)]);
    wkvh[idx] = (_Float16)(bf1(cw[CW_WK + idx]) * g);   // Wk|Wv contiguous
  } else {
    int i = idx - 131072;
    int d = i & 255;
    int q = (i >> 8) & 15;
    slots[i] = bf1(cw[CW_SLOTS + q * 256 + d]);
  }
}

// beta[c] = sum_d bin[d] * Wkv[c][d]  (512 cols)
__global__ void k_beta(const u16* __restrict__ cw, float* __restrict__ beta){
  int c = blockIdx.x * 256 + threadIdx.x;
  if (c >= 512) return;
  float a = 0.f;
  for (int d = 0; d < 256; d++)
    a = fmaf(bf1(cw[CW_BIN + d]), bf1(cw[CW_WK + c * 256 + d]), a);
  beta[c] = a;
}

__global__ void k_zero(float* __restrict__ p, int n){
  int i = blockIdx.x * 256 + threadIdx.x;
  if (i < n) p[i] = 0.f;
}

// ---------- K0: per-row LN stats (mu, rstd); 16 lanes per row ----------
__global__ __launch_bounds__(256) void k0_stats(
    const void* __restrict__ inp, const int* __restrict__ flag, float2* __restrict__ stats)
{
  int f32m = *flag;
  int g = blockIdx.x * 256 + threadIdx.x;
  int row = g >> 4, l = g & 15;
  float sum = 0.f, sq = 0.f;
  if (f32m){
    const float* rp = (const float*)inp + row * 256 + l * 16;
    #pragma unroll
    for (int i = 0; i < 4; i++){
      float4 v = ((const float4*)rp)[i];
      sum += v.x + v.y + v.z + v.w;
      sq = fmaf(v.x, v.x, sq); sq = fmaf(v.y, v.y, sq);
      sq = fmaf(v.z, v.z, sq); sq = fmaf(v.w, v.w, sq);
    }
  } else {
    const u16* rp = (const u16*)inp + row * 256 + l * 16;
    #pragma unroll
    for (int i = 0; i < 2; i++){
      uint4 u = ((const uint4*)rp)[i];
      unsigned w[4] = {u.x, u.y, u.z, u.w};
      #pragma unroll
      for (int p = 0; p < 4; p++){
        float a = bflo(w[p]), b = bfhi(w[p]);
        sum += a + b; sq = fmaf(a, a, sq); sq = fmaf(b, b, sq);
      }
    }
  }
  #pragma unroll
  for (int m = 1; m < 16; m <<= 1){ sum += __shfl_xor(sum, m); sq += __shfl_xor(sq, m); }
  if (l == 0){
    float mu = sum * (1.f/256.f);
    float var = sq * (1.f/256.f) - mu * mu;
    stats[row] = make_float2(mu, rsqrtf(var + 1e-5f));
  }
}

// ---------- K1: GEMM, stats precomputed; 128 rows/block ----------
// grid (1024 row-blocks of 128 rows, 2 n-blocks of 256 cols); wave owns 4 n-tiles
// out col<256 -> kh[row][col]; col>=256 -> vT[b][col-256][key]
__global__ __launch_bounds__(256) void k1_gemm(
    const void* __restrict__ inp, const int* __restrict__ flag,
    const float2* __restrict__ stats, const float* __restrict__ beta,
    const _Float16* __restrict__ wkvh, _Float16* __restrict__ kh, _Float16* __restrict__ vT)
{
  int f32m = *flag;
  int tid = threadIdx.x;
  int wv = tid >> 6, lane = tid & 63;
  int m16 = lane & 15, q4 = lane >> 4;
  int nb = blockIdx.y;
  long rowb0 = (long)blockIdx.x * 128;
  int colW = nb * 256 + wv * 64;                  // wave's base col

  // B-fragments (compiler keeps hot subset; rest re-fetched from L2)
  half8 bfr[4][8];
  #pragma unroll
  for (int nt = 0; nt < 4; nt++)
    #pragma unroll
    for (int s = 0; s < 8; s++)
      bfr[nt][s] = *(const half8*)(wkvh + (colW + nt * 16 + m16) * 256 + s * 32 + q4 * 8);

  float bet[4];
  #pragma unroll
  for (int nt = 0; nt < 4; nt++) bet[nt] = beta[colW + nt * 16 + m16];

  for (int rt = 0; rt < 8; rt++){
    long rowb = rowb0 + rt * 16;
    long myRow = rowb + m16;
    float2 st = stats[myRow];
    float mu = st.x, rstd = st.y;

    half8 af[8];
    if (f32m){
      const float* rp = (const float*)inp + myRow * 256 + q4 * 8;
      #pragma unroll
      for (int s = 0; s < 8; s++){
        float4 x0 = *(const float4*)(rp + s * 32);
        float4 x1 = *(const float4*)(rp + s * 32 + 4);
        af[s][0] = (_Float16)((x0.x - mu) * rstd); af[s][1] = (_Float16)((x0.y - mu) * rstd);
        af[s][2] = (_Float16)((x0.z - mu) * rstd); af[s][3] = (_Float16)((x0.w - mu) * rstd);
        af[s][4] = (_Float16)((x1.x - mu) * rstd); af[s][5] = (_Float16)((x1.y - mu) * rstd);
        af[s][6] = (_Float16)((x1.z - mu) * rstd); af[s][7] = (_Float16)((x1.w - mu) * rstd);
      }
    } else {
      const u16* rp = (const u16*)inp + myRow * 256 + q4 * 8;
      #pragma unroll
      for (int s = 0; s < 8; s++){
        uint4 xu = *(const uint4*)(rp + s * 32);
        unsigned xw[4] = {xu.x, xu.y, xu.z, xu.w};
        #pragma unroll
        for (int p = 0; p < 4; p++){
          af[s][2*p]   = (_Float16)((bflo(xw[p]) - mu) * rstd);
          af[s][2*p+1] = (_Float16)((bfhi(xw[p]) - mu) * rstd);
        }
      }
    }

    floatx4 acc[4];
    #pragma unroll
    for (int nt = 0; nt < 4; nt++){
      acc[nt][0] = bet[nt]; acc[nt][1] = bet[nt]; acc[nt][2] = bet[nt]; acc[nt][3] = bet[nt];
    }
    #pragma unroll
    for (int s = 0; s < 8; s++)
      #pragma unroll
      for (int nt = 0; nt < 4; nt++)
        acc[nt] = __builtin_amdgcn_mfma_f32_16x16x32_f16(af[s], bfr[nt][s], acc[nt], 0, 0, 0);

    if (nb == 0){
      long crow = rowb + q4 * 4;
      #pragma unroll
      for (int nt = 0; nt < 4; nt++)
        #pragma unroll
        for (int r = 0; r < 4; r++)
          kh[(crow + r) * 256 + colW + nt * 16 + m16] = (_Float16)acc[nt][r];
    } else {
      int b = (int)(rowb >> 12);
      int key = ((int)rowb & 4095) + q4 * 4;
      #pragma unroll
      for (int nt = 0; nt < 4; nt++){
        int cv = (colW - 256) + nt * 16 + m16;
        half4 pk;
        pk[0] = (_Float16)acc[nt][0]; pk[1] = (_Float16)acc[nt][1];
        pk[2] = (_Float16)acc[nt][2]; pk[3] = (_Float16)acc[nt][3];
        *(half4*)(vT + ((long)b * 256 + cv) * 4096 + key) = pk;
      }
    }
  }
}

// ---------- K2: slot LN + q projection ----------
__global__ __launch_bounds__(256) void k2_q(
    const float* __restrict__ slots, const u16* __restrict__ cw, _Float16* __restrict__ qh)
{
  const u16* gq = cw + CW_GS;
  const u16* bq = cw + CW_BS;
  const u16* Wq = cw + CW_WQ;
  int row = blockIdx.x, tid = threadIdx.x;
  int wv = tid >> 6, lane = tid & 63;
  float x = slots[row * 256 + tid];
  float s = x, s2 = x * x;
  #pragma unroll
  for (int m = 1; m < 64; m <<= 1){ s += __shfl_xor(s, m); s2 += __shfl_xor(s2, m); }
  __shared__ float red[8];
  if (lane == 0){ red[wv] = s; red[4 + wv] = s2; }
  __syncthreads();
  float tot  = red[0] + red[1] + red[2] + red[3];
  float tot2 = red[4] + red[5] + red[6] + red[7];
  float mu = tot * (1.f/256.f);
  float rstd = rsqrtf(tot2 * (1.f/256.f) - mu * mu + 1e-5f);
  __shared__ float sln[256];
  sln[tid] = (x - mu) * rstd * bf1(gq[tid]) + bf1(bq[tid]);
  __syncthreads();
  const u16* wr = Wq + tid * 256;
  float a = 0.f;
  for (int k = 0; k < 256; k += 8){
    uint4 wu = *(const uint4*)(wr + k);
    float4 l0 = *(const float4*)(sln + k);
    float4 l1 = *(const float4*)(sln + k + 4);
    a = dot8(wu, l0, l1, a);
  }
  qh[row * 256 + tid] = (_Float16)(a * 0.17677669529663687f);
}

// ---------- K3: logits(MFMA) + joint softmax + MFMA numer/denom ----------
// grid (nchunks, 32 batches); keys per chunk = g4count*32; wave w owns heads 2w,2w+1
__global__ __launch_bounds__(256) void k3_attn(
    const _Float16* __restrict__ kh, const _Float16* __restrict__ vT,
    const _Float16* __restrict__ qh,
    float* __restrict__ numer, float* __restrict__ denom,
    float* __restrict__ part, int use_part, int g4count,
    void* __restrict__ av_base, const int* __restrict__ flag, int lastIter)
{
  int f32m = *flag;
  int tid = threadIdx.x;
  int wv = tid >> 6, lane = tid & 63;
  int m16 = lane & 15, q4 = lane >> 4;
  int b = blockIdx.y, chunk = blockIdx.x;
  int kpc = g4count * 32;
  __shared__ float lds_l[32 * 129];               // [key 0..31][h*16+q]

  half8 qf[2];
  #pragma unroll
  for (int hh = 0; hh < 2; hh++){
    int h = wv * 2 + hh;
    qf[hh] = *(const half8*)(qh + (b * 16 + m16) * 256 + h * 32 + q4 * 8);
  }
  float pd[2] = {0.f, 0.f};
  floatx4 un[2][2];
  #pragma unroll
  for (int hh = 0; hh < 2; hh++)
    #pragma unroll
    for (int dt = 0; dt < 2; dt++) un[hh][dt] = (floatx4)0.f;

  floatx4 z4 = (floatx4)0.f;
  for (int g4 = 0; g4 < g4count; g4++){
    int key0 = chunk * kpc + g4 * 32;
    // phase A: logits for 32 keys x 2 heads per wave
    #pragma unroll
    for (int sub = 0; sub < 2; sub++){
      long rowb = (long)b * 4096 + key0 + sub * 16;
      #pragma unroll
      for (int hh = 0; hh < 2; hh++){
        int h = wv * 2 + hh;
        half8 af = *(const half8*)(kh + (rowb + m16) * 256 + h * 32 + q4 * 8);
        floatx4 d = __builtin_amdgcn_mfma_f32_16x16x32_f16(af, qf[hh], z4, 0, 0, 0);
        #pragma unroll
        for (int r = 0; r < 4; r++)
          lds_l[(sub * 16 + q4 * 4 + r) * 129 + h * 16 + m16] = d[r];
      }
    }
    __syncthreads();
    // phase B: per-key joint softmax over 128 (h,q); each thread does 2 keys
    {
      int qq = tid & 15;
      #pragma unroll
      for (int half_ = 0; half_ < 2; half_++){
        int kk = (tid >> 4) + half_ * 16;
        float l[8];
        #pragma unroll
        for (int h8 = 0; h8 < 8; h8++) l[h8] = lds_l[kk * 129 + h8 * 16 + qq];
        float M = l[0];
        #pragma unroll
        for (int h8 = 1; h8 < 8; h8++) M = fmaxf(M, l[h8]);
        #pragma unroll
        for (int msk = 1; msk < 16; msk <<= 1) M = fmaxf(M, __shfl_xor(M, msk));
        float p[8], sl = 0.f;
        #pragma unroll
        for (int h8 = 0; h8 < 8; h8++){ p[h8] = __expf(l[h8] - M); sl += p[h8]; }
        float St = sl;
        #pragma unroll
        for (int msk = 1; msk < 16; msk <<= 1) St += __shfl_xor(St, msk);
        float rS = 1.f / St;
        #pragma unroll
        for (int h8 = 0; h8 < 8; h8++) lds_l[kk * 129 + h8 * 16 + qq] = p[h8] * rS;
        if (lastIter){
          long idx = 131072 + ((long)b * 4096 + key0 + kk) * 16 + qq;
          float av = sl * rS;
          if (f32m) ((float*)av_base)[idx] = av;
          else      ((u16*)av_base)[idx]   = f2bf(av);
        }
      }
    }
    __syncthreads();
    // phase C: U[d][q] += vT[d][key] * P[key][q] via MFMA over 32 keys
    #pragma unroll
    for (int hh = 0; hh < 2; hh++){
      int h = wv * 2 + hh;
      float pv[8];
      #pragma unroll
      for (int j = 0; j < 8; j++) pv[j] = lds_l[(q4 * 8 + j) * 129 + h * 16 + m16];
      float ps = 0.f;
      #pragma unroll
      for (int j = 0; j < 8; j++) ps += pv[j];
      pd[hh] += ps;
      half8 bfr;
      #pragma unroll
      for (int j = 0; j < 8; j++) bfr[j] = (_Float16)pv[j];
      #pragma unroll
      for (int dt = 0; dt < 2; dt++){
        half8 afr = *(const half8*)(vT + ((long)b * 256 + h * 32 + dt * 16 + m16) * 4096 + key0 + q4 * 8);
        un[hh][dt] = __builtin_amdgcn_mfma_f32_16x16x32_f16(afr, bfr, un[hh][dt], 0, 0, 0);
      }
    }
    __syncthreads();
  }
  if (use_part){
    float* pn = part + (long)chunk * PART_STRIDE;
    #pragma unroll
    for (int hh = 0; hh < 2; hh++){
      int h = wv * 2 + hh;
      float t = pd[hh];
      t += __shfl_xor(t, 16); t += __shfl_xor(t, 32);
      if (q4 == 0) pn[131072 + (b * 8 + h) * 16 + m16] = t;
      #pragma unroll
      for (int dt = 0; dt < 2; dt++)
        *(floatx4*)(&pn[((b * 8 + h) * 16 + m16) * 32 + dt * 16 + q4 * 4]) = un[hh][dt];
    }
  } else {
    #pragma unroll
    for (int hh = 0; hh < 2; hh++){
      int h = wv * 2 + hh;
      float t = pd[hh];
      t += __shfl_xor(t, 16); t += __shfl_xor(t, 32);
      if (q4 == 0) atomicAdd(&denom[(b * 8 + h) * 16 + m16], t);
      #pragma unroll
      for (int dt = 0; dt < 2; dt++)
        #pragma unroll
        for (int r = 0; r < 4; r++)
          atomicAdd(&numer[((b * 8 + h) * 16 + m16) * 32 + dt * 16 + q4 * 4 + r], un[hh][dt][r]);
    }
  }
}

// ---------- reduce partial numer/denom ----------
__global__ void k_reduce(const float* __restrict__ part, float* __restrict__ numer, int npart){
  int i = blockIdx.x * 256 + threadIdx.x;
  if (i >= PART_STRIDE) return;
  float s = 0.f;
  for (int c = 0; c < npart; c++) s += part[(long)c * PART_STRIDE + i];
  numer[i] = s;   // denom is contiguous after numer
}

// ---------- K4a: GRU cell -> mid (f32) ----------
__global__ __launch_bounds__(256) void k4a_gru(
    const float* __restrict__ slots, const float* __restrict__ numer, const float* __restrict__ denom,
    const u16* __restrict__ cw, float* __restrict__ mid)
{
  const u16* wih = cw + CW_WIH;
  const u16* whh = cw + CW_WHH;
  const u16* bih = cw + CW_BIH;
  const u16* bhh = cw + CW_BHH;
  int jc = blockIdx.x, rg = blockIdx.y;
  int tid = threadIdx.x;
  __shared__ float u_s[8][256];
  __shared__ float h_s[8][256];
  {
    int hh = tid >> 5, dh = tid & 31;
    for (int i = 0; i < 8; i++){
      int row = rg * 8 + i;
      int b = row >> 4, slot = row & 15;
      float den = denom[(b * 8 + hh) * 16 + slot] + 1e-8f;
      u_s[i][tid] = numer[((b * 8 + hh) * 16 + slot) * 32 + dh] / den;
      h_s[i][tid] = slots[row * 256 + tid];
    }
  }
  __syncthreads();
  int rl = tid >> 5, jl = tid & 31;
  int j = jc * 32 + jl;
  int row = rg * 8 + rl;
  const u16* wir = wih + j * 256;
  const u16* wiz = wih + (256 + j) * 256;
  const u16* win = wih + (512 + j) * 256;
  const u16* whr = whh + j * 256;
  const u16* whz = whh + (256 + j) * 256;
  const u16* whn = whh + (512 + j) * 256;
  float air = 0, aiz = 0, ain = 0, ahr = 0, ahz = 0, ahn = 0;
  for (int k = 0; k < 256; k += 8){
    float4 u0 = *(const float4*)(&u_s[rl][k]);
    float4 u1 = *(const float4*)(&u_s[rl][k + 4]);
    float4 h0 = *(const float4*)(&h_s[rl][k]);
    float4 h1 = *(const float4*)(&h_s[rl][k + 4]);
    air = dot8(*(const uint4*)(wir + k), u0, u1, air);
    aiz = dot8(*(const uint4*)(wiz + k), u0, u1, aiz);
    ain = dot8(*(const uint4*)(win + k), u0, u1, ain);
    ahr = dot8(*(const uint4*)(whr + k), h0, h1, ahr);
    ahz = dot8(*(const uint4*)(whz + k), h0, h1, ahz);
    ahn = dot8(*(const uint4*)(whn + k), h0, h1, ahn);
  }
  float gr = air + bf1(bih[j])       + ahr + bf1(bhh[j]);
  float gz = aiz + bf1(bih[256 + j]) + ahz + bf1(bhh[256 + j]);
  float r = 1.f / (1.f + __expf(-gr));
  float z = 1.f / (1.f + __expf(-gz));
  float nn = tanhf(ain + bf1(bih[512 + j]) + r * (ahn + bf1(bhh[512 + j])));
  float h = h_s[rl][j];
  mid[row * 256 + j] = (1.f - z) * nn + z * h;
}

// ---------- K4b: LN + MLP + residual ----------
__global__ __launch_bounds__(256) void k4b_mlp(
    const float* __restrict__ mid, const u16* __restrict__ cw,
    float* __restrict__ slots, void* __restrict__ out_base,
    const int* __restrict__ flag, int lastIter)
{
  int f32m = *flag;
  const u16* gm = cw + CW_GM;
  const u16* bm = cw + CW_BM;
  const u16* w1 = cw + CW_W1;
  const u16* b1 = cw + CW_B1;
  const u16* w2 = cw + CW_W2;
  const u16* b2 = cw + CW_B2;
  int row = blockIdx.x, tid = threadIdx.x;
  int wv = tid >> 6, lane = tid & 63;
  float x = mid[row * 256 + tid];
  float s = x, s2 = x * x;
  #pragma unroll
  for (int m = 1; m < 64; m <<= 1){ s += __shfl_xor(s, m); s2 += __shfl_xor(s2, m); }
  __shared__ float red[8];
  if (lane == 0){ red[wv] = s; red[4 + wv] = s2; }
  __syncthreads();
  float tot  = red[0] + red[1] + red[2] + red[3];
  float tot2 = red[4] + red[5] + red[6] + red[7];
  float mu = tot * (1.f/256.f);
  float rstd = rsqrtf(tot2 * (1.f/256.f) - mu * mu + 1e-5f);
  __shared__ float ls[256];
  __shared__ float h1[512];
  ls[tid] = (x - mu) * rstd * bf1(gm[tid]) + bf1(bm[tid]);
  __syncthreads();
  const u16* w1a = w1 + tid * 256;
  const u16* w1b = w1 + (tid + 256) * 256;
  float a0 = 0.f, a1 = 0.f;
  for (int k = 0; k < 256; k += 8){
    float4 l0 = *(const float4*)(ls + k);
    float4 l1 = *(const float4*)(ls + k + 4);
    a0 = dot8(*(const uint4*)(w1a + k), l0, l1, a0);
    a1 = dot8(*(const uint4*)(w1b + k), l0, l1, a1);
  }
  h1[tid]       = fmaxf(a0 + bf1(b1[tid]), 0.f);
  h1[tid + 256] = fmaxf(a1 + bf1(b1[tid + 256]), 0.f);
  __syncthreads();
  const u16* w2r = w2 + tid * 512;
  float a = 0.f;
  for (int k = 0; k < 512; k += 8){
    float4 l0 = *(const float4*)(h1 + k);
    float4 l1 = *(const float4*)(h1 + k + 4);
    a = dot8(*(const uint4*)(w2r + k), l0, l1, a);
  }
  float res = x + a + bf1(b2[tid]);
  slots[row * 256 + tid] = res;
  if (lastIter){
    int idx = row * 256 + tid;
    if (f32m) ((float*)out_base)[idx] = res;
    else      ((u16*)out_base)[idx]   = f2bf(res);
  }
}

// ---------- launch ----------
extern "C" void kernel_launch(void* const* d_in, const int* in_sizes, int n_in,
                              void* d_out, int out_size, void* d_ws, size_t ws_size,
                              hipStream_t stream)
{
  char* ws = (char*)d_ws;
  int*  flagp    = (int*)ws;                        // [0,256)
  u16*  cw       = (u16*)(ws + 256);                // 1719808 -> 1720064
  _Float16* qh   = (_Float16*)(ws + 1720064);       //  262144 -> 1982208
  _Float16* wkvh = (_Float16*)(ws + 1982208);       //  262144 -> 2244352
  float* slots   = (float*)(ws + 2244352);          //  524288 -> 2768640
  float* mid     = (float*)(ws + 2768640);          //  524288 -> 3292928
  float* numer   = (float*)(ws + 3292928);          //  524288 -> 3817216
  float* denom   = (float*)(ws + 3817216);          //   16384 -> 3833600
  _Float16* kh   = (_Float16*)(ws + 3833600);       // 67108864 -> 70942464
  _Float16* vT   = (_Float16*)(ws + 70942464);      // 67108864 -> 138051328
  float* part    = (float*)(ws + 138051328);        // npart*540672 bytes if they fit
  // aliases (dead before the iteration loop):
  float2* stats  = (float2*)(ws + 2768640);         // 1 MB over mid+numer
  float*  beta   = (float*)(ws + 3817216);          // 2 KB in denom region

  // adaptive partial-buffer config
  const size_t base_end = 138051328UL;
  const size_t per_chunk = (size_t)PART_STRIDE * 4;
  int npart = 0;
  if      (ws_size >= base_end + 16 * per_chunk) npart = 16;
  else if (ws_size >= base_end +  8 * per_chunk) npart = 8;
  else if (ws_size >= base_end +  4 * per_chunk) npart = 4;
  int use_part = (npart > 0);
  int nchunks = use_part ? npart : 16;
  int g4count = (4096 / nchunks) / 32;

  CanonArgs ca;
  ca.p[0]  = d_in[0];   ca.p[1]  = d_in[2];   ca.p[2]  = d_in[3];
  ca.p[3]  = d_in[4];   ca.p[4]  = d_in[5];   ca.p[5]  = d_in[6];
  ca.p[6]  = d_in[7];   ca.p[7]  = d_in[8];   ca.p[8]  = d_in[9];
  ca.p[9]  = d_in[10];  ca.p[10] = d_in[11];  ca.p[11] = d_in[12];
  ca.p[12] = d_in[13];  ca.p[13] = d_in[14];  ca.p[14] = d_in[15];
  ca.p[15] = d_in[16];  ca.p[16] = d_in[17];  ca.p[17] = d_in[18];

  k_flag<<<1, 256, 0, stream>>>((const u16*)d_in[1], flagp);
  k_canon<<<(CW_TOTAL + 255) / 256, 256, 0, stream>>>(ca, flagp, cw);
  k_init<<<1024, 256, 0, stream>>>(cw, slots, wkvh);
  k_beta<<<2, 256, 0, stream>>>(cw, beta);
  k0_stats<<<8192, 256, 0, stream>>>(d_in[1], flagp, stats);
  k1_gemm<<<dim3(1024, 2), 256, 0, stream>>>(d_in[1], flagp, stats, beta, wkvh, kh, vT);
  for (int it = 0; it < 3; it++){
    int last = (it == 2) ? 1 : 0;
    k2_q<<<512, 256, 0, stream>>>(slots, cw, qh);
    if (!use_part) k_zero<<<528, 256, 0, stream>>>(numer, 135168);
    k3_attn<<<dim3(nchunks, 32), 256, 0, stream>>>(kh, vT, qh, numer, denom, part,
                                                   use_part, g4count, d_out, flagp, last);
    if (use_part) k_reduce<<<528, 256, 0, stream>>>(part, numer, npart);
    k4a_gru<<<dim3(8, 64), 256, 0, stream>>>(slots, numer, denom, cw, mid);
    k4b_mlp<<<512, 256, 0, stream>>>(mid, cw, slots, d_out, flagp, last);
  }
}

// Round 7
// 811.250 us; speedup vs baseline: 1.7601x; 1.0010x over previous
//
#include <hip/hip_runtime.h>
#include <stdint.h>

typedef unsigned short u16;
typedef __attribute__((ext_vector_type(8))) _Float16 half8;
typedef __attribute__((ext_vector_type(4))) _Float16 half4;
typedef __attribute__((ext_vector_type(4))) float floatx4;

// ---------- helpers ----------
__device__ inline float bflo(unsigned u){ return __uint_as_float(u << 16); }
__device__ inline float bfhi(unsigned u){ return __uint_as_float(u & 0xffff0000u); }
__device__ inline float bf1(u16 v){ return __uint_as_float(((unsigned)v) << 16); }
__device__ inline u16 f2bf(float f){
  unsigned u = __float_as_uint(f);
  u += 0x7fffu + ((u >> 16) & 1u);           // RNE
  return (u16)(u >> 16);
}
__device__ inline float dot8(uint4 w, float4 a, float4 b, float acc){
  acc = fmaf(bflo(w.x), a.x, acc); acc = fmaf(bfhi(w.x), a.y, acc);
  acc = fmaf(bflo(w.y), a.z, acc); acc = fmaf(bfhi(w.y), a.w, acc);
  acc = fmaf(bflo(w.z), b.x, acc); acc = fmaf(bfhi(w.z), b.y, acc);
  acc = fmaf(bflo(w.w), b.z, acc); acc = fmaf(bfhi(w.w), b.w, acc);
  return acc;
}

// canonical weight buffer offsets (u16 elements), d_in order (skipping inputs)
#define CW_SLOTS 0
#define CW_GIN   4096
#define CW_BIN   4352
#define CW_GS    4608
#define CW_BS    4864
#define CW_GM    5120
#define CW_BM    5376
#define CW_WQ    5632
#define CW_WK    71168
#define CW_WV    136704
#define CW_WIH   202240
#define CW_WHH   398848
#define CW_BIH   595456
#define CW_BHH   596224
#define CW_W1    596992
#define CW_B1    728064
#define CW_W2    728576
#define CW_B2    859648
#define CW_TOTAL 859904

// ---------- dtype probe ----------
__global__ void k_flag(const u16* __restrict__ probe, int* __restrict__ flag){
  int t = threadIdx.x;
  int bad = 0;
  #pragma unroll
  for (int i = 0; i < 4; i++){
    float x = bf1(probe[t + i * 256]);
    if (!(fabsf(x) < 1e6f)) bad = 1;
  }
  __shared__ int s;
  if (t == 0) s = 0;
  __syncthreads();
  if (bad) atomicOr(&s, 1);
  __syncthreads();
  if (t == 0) *flag = s;
}

// ---------- canonicalize all weight/bias arrays to bf16 in ws ----------
struct CanonArgs { const void* p[18]; };

__global__ void k_canon(CanonArgs a, const int* __restrict__ flag, u16* __restrict__ cw){
  const int off[19] = {CW_SLOTS, CW_GIN, CW_BIN, CW_GS, CW_BS, CW_GM, CW_BM, CW_WQ,
                       CW_WK, CW_WV, CW_WIH, CW_WHH, CW_BIH, CW_BHH, CW_W1, CW_B1,
                       CW_W2, CW_B2, CW_TOTAL};
  int i = blockIdx.x * 256 + threadIdx.x;
  if (i >= CW_TOTAL) return;
  int f32m = *flag;
  int j = 0;
  while (i >= off[j + 1]) j++;
  int local = i - off[j];
  float v = f32m ? ((const float*)a.p[j])[local] : bf1(((const u16*)a.p[j])[local]);
  cw[i] = f2bf(v);
}

// ---------- init: wkvh[c][d] = Wkv[c][d]*gin[d] (fp16); broadcast slots -> f32 ----------
__global__ void k_init(const u16* __restrict__ cw, float* __restrict__ slots,
                       _Float16* __restrict__ wkvh)
{
  int idx = blockIdx.x * 256 + threadIdx.x;      // 0..262143
  if (idx < 131072){
    float g = bf1(cw[CW_GIN + (idx & 255)]);
    wkvh[idx] = (_Float16)(bf1(cw[CW_WK + idx]) * g);   // Wk|Wv contiguous
  } else {
    int i = idx - 131072;
    int d = i & 255;
    int q = (i >> 8) & 15;
    slots[i] = bf1(cw[CW_SLOTS + q * 256 + d]);
  }
}

// beta[c] = sum_d bin[d] * Wkv[c][d]  (512 cols)
__global__ void k_beta(const u16* __restrict__ cw, float* __restrict__ beta){
  int c = blockIdx.x * 256 + threadIdx.x;
  if (c >= 512) return;
  float a = 0.f;
  for (int d = 0; d < 256; d++)
    a = fmaf(bf1(cw[CW_BIN + d]), bf1(cw[CW_WK + c * 256 + d]), a);
  beta[c] = a;
}

__global__ void k_zero(float* __restrict__ p, int n){
  int i = blockIdx.x * 256 + threadIdx.x;
  if (i < n) p[i] = 0.f;
}

// ---------- K0: per-row LN stats (mu, rstd); 16 lanes per row ----------
__global__ __launch_bounds__(256) void k0_stats(
    const void* __restrict__ inp, const int* __restrict__ flag, float2* __restrict__ stats)
{
  int f32m = *flag;
  int g = blockIdx.x * 256 + threadIdx.x;
  int row = g >> 4, l = g & 15;
  float sum = 0.f, sq = 0.f;
  if (f32m){
    const float* rp = (const float*)inp + row * 256 + l * 16;
    #pragma unroll
    for (int i = 0; i < 4; i++){
      float4 v = ((const float4*)rp)[i];
      sum += v.x + v.y + v.z + v.w;
      sq = fmaf(v.x, v.x, sq); sq = fmaf(v.y, v.y, sq);
      sq = fmaf(v.z, v.z, sq); sq = fmaf(v.w, v.w, sq);
    }
  } else {
    const u16* rp = (const u16*)inp + row * 256 + l * 16;
    #pragma unroll
    for (int i = 0; i < 2; i++){
      uint4 u = ((const uint4*)rp)[i];
      unsigned w[4] = {u.x, u.y, u.z, u.w};
      #pragma unroll
      for (int p = 0; p < 4; p++){
        float a = bflo(w[p]), b = bfhi(w[p]);
        sum += a + b; sq = fmaf(a, a, sq); sq = fmaf(b, b, sq);
      }
    }
  }
  #pragma unroll
  for (int m = 1; m < 16; m <<= 1){ sum += __shfl_xor(sum, m); sq += __shfl_xor(sq, m); }
  if (l == 0){
    float mu = sum * (1.f/256.f);
    float var = sq * (1.f/256.f) - mu * mu;
    stats[row] = make_float2(mu, rsqrtf(var + 1e-5f));
  }
}

// ---------- K1: GEMM, stats precomputed; 128 rows/block ----------
__global__ __launch_bounds__(256) void k1_gemm(
    const void* __restrict__ inp, const int* __restrict__ flag,
    const float2* __restrict__ stats, const float* __restrict__ beta,
    const _Float16* __restrict__ wkvh, _Float16* __restrict__ kh, _Float16* __restrict__ vT)
{
  int f32m = *flag;
  int tid = threadIdx.x;
  int wv = tid >> 6, lane = tid & 63;
  int m16 = lane & 15, q4 = lane >> 4;
  int nb = blockIdx.y;
  long rowb0 = (long)blockIdx.x * 128;
  int colW = nb * 256 + wv * 64;                  // wave's base col

  half8 bfr[4][8];
  #pragma unroll
  for (int nt = 0; nt < 4; nt++)
    #pragma unroll
    for (int s = 0; s < 8; s++)
      bfr[nt][s] = *(const half8*)(wkvh + (colW + nt * 16 + m16) * 256 + s * 32 + q4 * 8);

  float bet[4];
  #pragma unroll
  for (int nt = 0; nt < 4; nt++) bet[nt] = beta[colW + nt * 16 + m16];

  for (int rt = 0; rt < 8; rt++){
    long rowb = rowb0 + rt * 16;
    long myRow = rowb + m16;
    float2 st = stats[myRow];
    float mu = st.x, rstd = st.y;

    half8 af[8];
    if (f32m){
      const float* rp = (const float*)inp + myRow * 256 + q4 * 8;
      #pragma unroll
      for (int s = 0; s < 8; s++){
        float4 x0 = *(const float4*)(rp + s * 32);
        float4 x1 = *(const float4*)(rp + s * 32 + 4);
        af[s][0] = (_Float16)((x0.x - mu) * rstd); af[s][1] = (_Float16)((x0.y - mu) * rstd);
        af[s][2] = (_Float16)((x0.z - mu) * rstd); af[s][3] = (_Float16)((x0.w - mu) * rstd);
        af[s][4] = (_Float16)((x1.x - mu) * rstd); af[s][5] = (_Float16)((x1.y - mu) * rstd);
        af[s][6] = (_Float16)((x1.z - mu) * rstd); af[s][7] = (_Float16)((x1.w - mu) * rstd);
      }
    } else {
      const u16* rp = (const u16*)inp + myRow * 256 + q4 * 8;
      #pragma unroll
      for (int s = 0; s < 8; s++){
        uint4 xu = *(const uint4*)(rp + s * 32);
        unsigned xw[4] = {xu.x, xu.y, xu.z, xu.w};
        #pragma unroll
        for (int p = 0; p < 4; p++){
          af[s][2*p]   = (_Float16)((bflo(xw[p]) - mu) * rstd);
          af[s][2*p+1] = (_Float16)((bfhi(xw[p]) - mu) * rstd);
        }
      }
    }

    floatx4 acc[4];
    #pragma unroll
    for (int nt = 0; nt < 4; nt++){
      acc[nt][0] = bet[nt]; acc[nt][1] = bet[nt]; acc[nt][2] = bet[nt]; acc[nt][3] = bet[nt];
    }
    #pragma unroll
    for (int s = 0; s < 8; s++)
      #pragma unroll
      for (int nt = 0; nt < 4; nt++)
        acc[nt] = __builtin_amdgcn_mfma_f32_16x16x32_f16(af[s], bfr[nt][s], acc[nt], 0, 0, 0);

    if (nb == 0){
      long crow = rowb + q4 * 4;
      #pragma unroll
      for (int nt = 0; nt < 4; nt++)
        #pragma unroll
        for (int r = 0; r < 4; r++)
          kh[(crow + r) * 256 + colW + nt * 16 + m16] = (_Float16)acc[nt][r];
    } else {
      int b = (int)(rowb >> 12);
      int key = ((int)rowb & 4095) + q4 * 4;
      #pragma unroll
      for (int nt = 0; nt < 4; nt++){
        int cv = (colW - 256) + nt * 16 + m16;
        half4 pk;
        pk[0] = (_Float16)acc[nt][0]; pk[1] = (_Float16)acc[nt][1];
        pk[2] = (_Float16)acc[nt][2]; pk[3] = (_Float16)acc[nt][3];
        *(half4*)(vT + ((long)b * 256 + cv) * 4096 + key) = pk;
      }
    }
  }
}

// ---------- K2: slot LN + q projection ----------
__global__ __launch_bounds__(256) void k2_q(
    const float* __restrict__ slots, const u16* __restrict__ cw, _Float16* __restrict__ qh)
{
  const u16* gq = cw + CW_GS;
  const u16* bq = cw + CW_BS;
  const u16* Wq = cw + CW_WQ;
  int row = blockIdx.x, tid = threadIdx.x;
  int wv = tid >> 6, lane = tid & 63;
  float x = slots[row * 256 + tid];
  float s = x, s2 = x * x;
  #pragma unroll
  for (int m = 1; m < 64; m <<= 1){ s += __shfl_xor(s, m); s2 += __shfl_xor(s2, m); }
  __shared__ float red[8];
  if (lane == 0){ red[wv] = s; red[4 + wv] = s2; }
  __syncthreads();
  float tot  = red[0] + red[1] + red[2] + red[3];
  float tot2 = red[4] + red[5] + red[6] + red[7];
  float mu = tot * (1.f/256.f);
  float rstd = rsqrtf(tot2 * (1.f/256.f) - mu * mu + 1e-5f);
  __shared__ float sln[256];
  sln[tid] = (x - mu) * rstd * bf1(gq[tid]) + bf1(bq[tid]);
  __syncthreads();
  const u16* wr = Wq + tid * 256;
  float a = 0.f;
  for (int k = 0; k < 256; k += 8){
    uint4 wu = *(const uint4*)(wr + k);
    float4 l0 = *(const float4*)(sln + k);
    float4 l1 = *(const float4*)(sln + k + 4);
    a = dot8(wu, l0, l1, a);
  }
  qh[row * 256 + tid] = (_Float16)(a * 0.17677669529663687f);
}

// ---------- K3: logits(MFMA) + joint softmax + MFMA numer (fp16 partials -> d_out scratch) ----------
// grid (16 chunks of 256 keys, 32 batches); wave w owns heads 2w,2w+1
__global__ __launch_bounds__(256) void k3_attn(
    const _Float16* __restrict__ kh, const _Float16* __restrict__ vT,
    const _Float16* __restrict__ qh,
    float* __restrict__ denom, void* __restrict__ out_scratch,
    const int* __restrict__ flag)
{
  int f32m = *flag;
  int tid = threadIdx.x;
  int wv = tid >> 6, lane = tid & 63;
  int m16 = lane & 15, q4 = lane >> 4;
  int b = blockIdx.y, chunk = blockIdx.x;
  __shared__ float lds_l[32 * 129];               // [key 0..31][h*16+q]

  half8 qf[2];
  #pragma unroll
  for (int hh = 0; hh < 2; hh++){
    int h = wv * 2 + hh;
    qf[hh] = *(const half8*)(qh + (b * 16 + m16) * 256 + h * 32 + q4 * 8);
  }
  float pd[2] = {0.f, 0.f};
  floatx4 un[2][2];
  #pragma unroll
  for (int hh = 0; hh < 2; hh++)
    #pragma unroll
    for (int dt = 0; dt < 2; dt++) un[hh][dt] = (floatx4)0.f;

  floatx4 z4 = (floatx4)0.f;
  for (int g4 = 0; g4 < 8; g4++){
    int key0 = chunk * 256 + g4 * 32;
    // phase A: logits for 32 keys x 2 heads per wave
    #pragma unroll
    for (int sub = 0; sub < 2; sub++){
      long rowb = (long)b * 4096 + key0 + sub * 16;
      #pragma unroll
      for (int hh = 0; hh < 2; hh++){
        int h = wv * 2 + hh;
        half8 af = *(const half8*)(kh + (rowb + m16) * 256 + h * 32 + q4 * 8);
        floatx4 d = __builtin_amdgcn_mfma_f32_16x16x32_f16(af, qf[hh], z4, 0, 0, 0);
        #pragma unroll
        for (int r = 0; r < 4; r++)
          lds_l[(sub * 16 + q4 * 4 + r) * 129 + h * 16 + m16] = d[r];
      }
    }
    __syncthreads();
    // phase B: per-key joint softmax over 128 (h,q); each thread does 2 keys
    {
      int qq = tid & 15;
      #pragma unroll
      for (int half_ = 0; half_ < 2; half_++){
        int kk = (tid >> 4) + half_ * 16;
        float l[8];
        #pragma unroll
        for (int h8 = 0; h8 < 8; h8++) l[h8] = lds_l[kk * 129 + h8 * 16 + qq];
        float M = l[0];
        #pragma unroll
        for (int h8 = 1; h8 < 8; h8++) M = fmaxf(M, l[h8]);
        #pragma unroll
        for (int msk = 1; msk < 16; msk <<= 1) M = fmaxf(M, __shfl_xor(M, msk));
        float p[8], sl = 0.f;
        #pragma unroll
        for (int h8 = 0; h8 < 8; h8++){ p[h8] = __expf(l[h8] - M); sl += p[h8]; }
        float St = sl;
        #pragma unroll
        for (int msk = 1; msk < 16; msk <<= 1) St += __shfl_xor(St, msk);
        float rS = 1.f / St;
        #pragma unroll
        for (int h8 = 0; h8 < 8; h8++) lds_l[kk * 129 + h8 * 16 + qq] = p[h8] * rS;
      }
    }
    __syncthreads();
    // phase C: U[d][q] += vT[d][key] * P[key][q] via MFMA over 32 keys
    #pragma unroll
    for (int hh = 0; hh < 2; hh++){
      int h = wv * 2 + hh;
      float pv[8];
      #pragma unroll
      for (int j = 0; j < 8; j++) pv[j] = lds_l[(q4 * 8 + j) * 129 + h * 16 + m16];
      float ps = 0.f;
      #pragma unroll
      for (int j = 0; j < 8; j++) ps += pv[j];
      pd[hh] += ps;
      half8 bfr;
      #pragma unroll
      for (int j = 0; j < 8; j++) bfr[j] = (_Float16)pv[j];
      #pragma unroll
      for (int dt = 0; dt < 2; dt++){
        half8 afr = *(const half8*)(vT + ((long)b * 256 + h * 32 + dt * 16 + m16) * 4096 + key0 + q4 * 8);
        un[hh][dt] = __builtin_amdgcn_mfma_f32_16x16x32_f16(afr, bfr, un[hh][dt], 0, 0, 0);
      }
    }
    __syncthreads();
  }
  // fp16 numer partials into d_out's attn_vis region (scratch until k3_av rewrites it)
  _Float16* pp = (_Float16*)((u16*)out_scratch + (f32m ? 262144 : 131072))
                 + (long)chunk * 131072;
  #pragma unroll
  for (int hh = 0; hh < 2; hh++){
    int h = wv * 2 + hh;
    float t = pd[hh];
    t += __shfl_xor(t, 16); t += __shfl_xor(t, 32);
    if (q4 == 0) atomicAdd(&denom[(b * 8 + h) * 16 + m16], t);
    #pragma unroll
    for (int dt = 0; dt < 2; dt++){
      half4 st;
      #pragma unroll
      for (int r = 0; r < 4; r++) st[r] = (_Float16)un[hh][dt][r];
      *(half4*)(pp + ((b * 8 + h) * 16 + m16) * 32 + dt * 16 + q4 * 4) = st;
    }
  }
}

// ---------- reduce fp16 numer partials (16 chunks) -> f32 numer ----------
__global__ void k_reduce(const void* __restrict__ out_scratch, const int* __restrict__ flag,
                         float* __restrict__ numer){
  int i = blockIdx.x * 256 + threadIdx.x;        // 0..131071
  int f32m = *flag;
  const _Float16* pp = (const _Float16*)((const u16*)out_scratch + (f32m ? 262144 : 131072));
  float s = 0.f;
  #pragma unroll
  for (int c = 0; c < 16; c++) s += (float)pp[(long)c * 131072 + i];
  numer[i] = s;
}

// ---------- K3av: recompute logits+softmax, write real attn_vis (last iter) ----------
__global__ __launch_bounds__(256) void k3_av(
    const _Float16* __restrict__ kh, const _Float16* __restrict__ qh,
    void* __restrict__ av_base, const int* __restrict__ flag)
{
  int f32m = *flag;
  int tid = threadIdx.x;
  int wv = tid >> 6, lane = tid & 63;
  int m16 = lane & 15, q4 = lane >> 4;
  int b = blockIdx.y, chunk = blockIdx.x;
  __shared__ float lds_l[32 * 129];

  half8 qf[2];
  #pragma unroll
  for (int hh = 0; hh < 2; hh++){
    int h = wv * 2 + hh;
    qf[hh] = *(const half8*)(qh + (b * 16 + m16) * 256 + h * 32 + q4 * 8);
  }
  floatx4 z4 = (floatx4)0.f;
  for (int g4 = 0; g4 < 8; g4++){
    int key0 = chunk * 256 + g4 * 32;
    #pragma unroll
    for (int sub = 0; sub < 2; sub++){
      long rowb = (long)b * 4096 + key0 + sub * 16;
      #pragma unroll
      for (int hh = 0; hh < 2; hh++){
        int h = wv * 2 + hh;
        half8 af = *(const half8*)(kh + (rowb + m16) * 256 + h * 32 + q4 * 8);
        floatx4 d = __builtin_amdgcn_mfma_f32_16x16x32_f16(af, qf[hh], z4, 0, 0, 0);
        #pragma unroll
        for (int r = 0; r < 4; r++)
          lds_l[(sub * 16 + q4 * 4 + r) * 129 + h * 16 + m16] = d[r];
      }
    }
    __syncthreads();
    {
      int qq = tid & 15;
      #pragma unroll
      for (int half_ = 0; half_ < 2; half_++){
        int kk = (tid >> 4) + half_ * 16;
        float l[8];
        #pragma unroll
        for (int h8 = 0; h8 < 8; h8++) l[h8] = lds_l[kk * 129 + h8 * 16 + qq];
        float M = l[0];
        #pragma unroll
        for (int h8 = 1; h8 < 8; h8++) M = fmaxf(M, l[h8]);
        #pragma unroll
        for (int msk = 1; msk < 16; msk <<= 1) M = fmaxf(M, __shfl_xor(M, msk));
        float sl = 0.f;
        #pragma unroll
        for (int h8 = 0; h8 < 8; h8++) sl += __expf(l[h8] - M);
        float St = sl;
        #pragma unroll
        for (int msk = 1; msk < 16; msk <<= 1) St += __shfl_xor(St, msk);
        float av = sl / St;
        long idx = 131072 + ((long)b * 4096 + key0 + kk) * 16 + qq;
        if (f32m) ((float*)av_base)[idx] = av;
        else      ((u16*)av_base)[idx]   = f2bf(av);
      }
    }
    __syncthreads();
  }
}

// ---------- K4a: GRU cell -> mid (f32) ----------
__global__ __launch_bounds__(256) void k4a_gru(
    const float* __restrict__ slots, const float* __restrict__ numer, const float* __restrict__ denom,
    const u16* __restrict__ cw, float* __restrict__ mid)
{
  const u16* wih = cw + CW_WIH;
  const u16* whh = cw + CW_WHH;
  const u16* bih = cw + CW_BIH;
  const u16* bhh = cw + CW_BHH;
  int jc = blockIdx.x, rg = blockIdx.y;
  int tid = threadIdx.x;
  __shared__ float u_s[8][256];
  __shared__ float h_s[8][256];
  {
    int hh = tid >> 5, dh = tid & 31;
    for (int i = 0; i < 8; i++){
      int row = rg * 8 + i;
      int b = row >> 4, slot = row & 15;
      float den = denom[(b * 8 + hh) * 16 + slot] + 1e-8f;
      u_s[i][tid] = numer[((b * 8 + hh) * 16 + slot) * 32 + dh] / den;
      h_s[i][tid] = slots[row * 256 + tid];
    }
  }
  __syncthreads();
  int rl = tid >> 5, jl = tid & 31;
  int j = jc * 32 + jl;
  int row = rg * 8 + rl;
  const u16* wir = wih + j * 256;
  const u16* wiz = wih + (256 + j) * 256;
  const u16* win = wih + (512 + j) * 256;
  const u16* whr = whh + j * 256;
  const u16* whz = whh + (256 + j) * 256;
  const u16* whn = whh + (512 + j) * 256;
  float air = 0, aiz = 0, ain = 0, ahr = 0, ahz = 0, ahn = 0;
  for (int k = 0; k < 256; k += 8){
    float4 u0 = *(const float4*)(&u_s[rl][k]);
    float4 u1 = *(const float4*)(&u_s[rl][k + 4]);
    float4 h0 = *(const float4*)(&h_s[rl][k]);
    float4 h1 = *(const float4*)(&h_s[rl][k + 4]);
    air = dot8(*(const uint4*)(wir + k), u0, u1, air);
    aiz = dot8(*(const uint4*)(wiz + k), u0, u1, aiz);
    ain = dot8(*(const uint4*)(win + k), u0, u1, ain);
    ahr = dot8(*(const uint4*)(whr + k), h0, h1, ahr);
    ahz = dot8(*(const uint4*)(whz + k), h0, h1, ahz);
    ahn = dot8(*(const uint4*)(whn + k), h0, h1, ahn);
  }
  float gr = air + bf1(bih[j])       + ahr + bf1(bhh[j]);
  float gz = aiz + bf1(bih[256 + j]) + ahz + bf1(bhh[256 + j]);
  float r = 1.f / (1.f + __expf(-gr));
  float z = 1.f / (1.f + __expf(-gz));
  float nn = tanhf(ain + bf1(bih[512 + j]) + r * (ahn + bf1(bhh[512 + j])));
  float h = h_s[rl][j];
  mid[row * 256 + j] = (1.f - z) * nn + z * h;
}

// ---------- K4b: LN + MLP + residual ----------
__global__ __launch_bounds__(256) void k4b_mlp(
    const float* __restrict__ mid, const u16* __restrict__ cw,
    float* __restrict__ slots, void* __restrict__ out_base,
    const int* __restrict__ flag, int lastIter)
{
  int f32m = *flag;
  const u16* gm = cw + CW_GM;
  const u16* bm = cw + CW_BM;
  const u16* w1 = cw + CW_W1;
  const u16* b1 = cw + CW_B1;
  const u16* w2 = cw + CW_W2;
  const u16* b2 = cw + CW_B2;
  int row = blockIdx.x, tid = threadIdx.x;
  int wv = tid >> 6, lane = tid & 63;
  float x = mid[row * 256 + tid];
  float s = x, s2 = x * x;
  #pragma unroll
  for (int m = 1; m < 64; m <<= 1){ s += __shfl_xor(s, m); s2 += __shfl_xor(s2, m); }
  __shared__ float red[8];
  if (lane == 0){ red[wv] = s; red[4 + wv] = s2; }
  __syncthreads();
  float tot  = red[0] + red[1] + red[2] + red[3];
  float tot2 = red[4] + red[5] + red[6] + red[7];
  float mu = tot * (1.f/256.f);
  float rstd = rsqrtf(tot2 * (1.f/256.f) - mu * mu + 1e-5f);
  __shared__ float ls[256];
  __shared__ float h1[512];
  ls[tid] = (x - mu) * rstd * bf1(gm[tid]) + bf1(bm[tid]);
  __syncthreads();
  const u16* w1a = w1 + tid * 256;
  const u16* w1b = w1 + (tid + 256) * 256;
  float a0 = 0.f, a1 = 0.f;
  for (int k = 0; k < 256; k += 8){
    float4 l0 = *(const float4*)(ls + k);
    float4 l1 = *(const float4*)(ls + k + 4);
    a0 = dot8(*(const uint4*)(w1a + k), l0, l1, a0);
    a1 = dot8(*(const uint4*)(w1b + k), l0, l1, a1);
  }
  h1[tid]       = fmaxf(a0 + bf1(b1[tid]), 0.f);
  h1[tid + 256] = fmaxf(a1 + bf1(b1[tid + 256]), 0.f);
  __syncthreads();
  const u16* w2r = w2 + tid * 512;
  float a = 0.f;
  for (int k = 0; k < 512; k += 8){
    float4 l0 = *(const float4*)(h1 + k);
    float4 l1 = *(const float4*)(h1 + k + 4);
    a = dot8(*(const uint4*)(w2r + k), l0, l1, a);
  }
  float res = x + a + bf1(b2[tid]);
  slots[row * 256 + tid] = res;
  if (lastIter){
    int idx = row * 256 + tid;
    if (f32m) ((float*)out_base)[idx] = res;
    else      ((u16*)out_base)[idx]   = f2bf(res);
  }
}

// ---------- launch ----------
extern "C" void kernel_launch(void* const* d_in, const int* in_sizes, int n_in,
                              void* d_out, int out_size, void* d_ws, size_t ws_size,
                              hipStream_t stream)
{
  char* ws = (char*)d_ws;
  int*  flagp    = (int*)ws;                        // [0,256)
  u16*  cw       = (u16*)(ws + 256);                // 1719808 -> 1720064
  _Float16* qh   = (_Float16*)(ws + 1720064);       //  262144 -> 1982208
  _Float16* wkvh = (_Float16*)(ws + 1982208);       //  262144 -> 2244352
  float* slots   = (float*)(ws + 2244352);          //  524288 -> 2768640
  float* mid     = (float*)(ws + 2768640);          //  524288 -> 3292928
  float* numer   = (float*)(ws + 3292928);          //  524288 -> 3817216
  float* denom   = (float*)(ws + 3817216);          //   16384 -> 3833600
  _Float16* kh   = (_Float16*)(ws + 3833600);       // 67108864 -> 70942464
  _Float16* vT   = (_Float16*)(ws + 70942464);      // 67108864 -> 138051328
  // aliases (dead before the iteration loop):
  float2* stats  = (float2*)(ws + 2768640);         // 1 MB over mid+numer
  float*  beta   = (float*)(ws + 3817216);          // 2 KB in denom region

  CanonArgs ca;
  ca.p[0]  = d_in[0];   ca.p[1]  = d_in[2];   ca.p[2]  = d_in[3];
  ca.p[3]  = d_in[4];   ca.p[4]  = d_in[5];   ca.p[5]  = d_in[6];
  ca.p[6]  = d_in[7];   ca.p[7]  = d_in[8];   ca.p[8]  = d_in[9];
  ca.p[9]  = d_in[10];  ca.p[10] = d_in[11];  ca.p[11] = d_in[12];
  ca.p[12] = d_in[13];  ca.p[13] = d_in[14];  ca.p[14] = d_in[15];
  ca.p[15] = d_in[16];  ca.p[16] = d_in[17];  ca.p[17] = d_in[18];

  k_flag<<<1, 256, 0, stream>>>((const u16*)d_in[1], flagp);
  k_canon<<<(CW_TOTAL + 255) / 256, 256, 0, stream>>>(ca, flagp, cw);
  k_init<<<1024, 256, 0, stream>>>(cw, slots, wkvh);
  k_beta<<<2, 256, 0, stream>>>(cw, beta);
  k0_stats<<<8192, 256, 0, stream>>>(d_in[1], flagp, stats);
  k1_gemm<<<dim3(1024, 2), 256, 0, stream>>>(d_in[1], flagp, stats, beta, wkvh, kh, vT);
  for (int it = 0; it < 3; it++){
    int last = (it == 2) ? 1 : 0;
    k2_q<<<512, 256, 0, stream>>>(slots, cw, qh);
    k_zero<<<16, 256, 0, stream>>>(denom, 4096);
    k3_attn<<<dim3(16, 32), 256, 0, stream>>>(kh, vT, qh, denom, d_out, flagp);
    k_reduce<<<512, 256, 0, stream>>>(d_out, flagp, numer);
    if (last) k3_av<<<dim3(16, 32), 256, 0, stream>>>(kh, qh, d_out, flagp);
    k4a_gru<<<dim3(8, 64), 256, 0, stream>>>(slots, numer, denom, cw, mid);
    k4b_mlp<<<512, 256, 0, stream>>>(mid, cw, slots, d_out, flagp, last);
  }
}